// Round 11
// baseline (545.702 us; speedup 1.0000x reference)
//
#include <hip/hip_runtime.h>
#include <cstdint>
#include <cstddef>

#define NEG_SLOPE 0.2f

typedef __attribute__((ext_vector_type(8))) short bh8;     // 8 bf16 in 4 VGPRs
typedef __attribute__((ext_vector_type(16))) float f32x16; // MFMA 32x32 accumulator

// split f32 -> bf16 hi + bf16 lo (x ~= hi + lo, residual ~2^-17 relative)
__device__ inline void splitf(float x, short& hi, short& lo) {
    uint32_t u = __float_as_uint(x);
    uint32_t rh = (u + 0x7FFFu + ((u >> 16) & 1u)) & 0xFFFF0000u;
    hi = (short)(rh >> 16);
    float rem = x - __uint_as_float(rh);
    uint32_t u2 = __float_as_uint(rem);
    lo = (short)((u2 + 0x7FFFu + ((u2 >> 16) & 1u)) >> 16);
}

__device__ inline unsigned short f2bf(float x) {   // round-to-nearest-even bf16
    uint32_t u = __float_as_uint(x);
    return (unsigned short)((u + 0x7FFFu + ((u >> 16) & 1u)) >> 16);
}

// ---------------------------------------------------------------- sentinel
__global__ void sentinel_kernel(float* __restrict__ out, int n) {
    int i = blockIdx.x * blockDim.x + threadIdx.x;
    if (i < n) out[i] = 12345.0f;
}

// ------------------------------------------------- CSR build v3 (bucketed)
// bucket = dst >> 9 (512 nodes); pair = (dst&511)<<17 | src  (needs nodes<2^17)
#define HIST_CH 8192
__global__ void bucket_count_kernel(const int* __restrict__ dst, int* __restrict__ bcnt,
                                    int ne, int nb) {
    __shared__ int hist[256];
    const int tid = threadIdx.x;
    hist[tid] = 0;
    __syncthreads();
    int e0 = blockIdx.x * HIST_CH;
    for (int i = tid; i < HIST_CH; i += 256) {
        int e = e0 + i;
        if (e < ne) atomicAdd(&hist[dst[e] >> 9], 1);
    }
    __syncthreads();
    if (tid < nb && hist[tid] > 0) atomicAdd(&bcnt[tid], hist[tid]);
}

// scan over <=256 bucket counts; boff[0..n], boff[n]=total
__global__ void scan256_kernel(const int* __restrict__ bcnt, int* __restrict__ boff, int n) {
    const int tid = threadIdx.x, lane = tid & 63, wid = tid >> 6;
    __shared__ int wt[4];
    int v = (tid < n) ? bcnt[tid] : 0;
    int incl = v;
    #pragma unroll
    for (int o = 1; o < 64; o <<= 1) {
        int t = __shfl_up(incl, o);
        if (lane >= o) incl += t;
    }
    if (lane == 63) wt[wid] = incl;
    __syncthreads();
    if (tid < 4) {
        int w = wt[tid], winc = w;
        #pragma unroll
        for (int o = 1; o < 4; o <<= 1) {
            int t = __shfl_up(winc, o);
            if (tid >= o) winc += t;
        }
        wt[tid] = winc - w;
    }
    __syncthreads();
    int excl = wt[wid] + incl - v;
    if (tid < n) boff[tid] = excl;
    if (tid == n - 1) boff[n] = excl + v;
}

#define SCAT_CH 4096
__global__ void bucket_scatter_kernel(const int* __restrict__ src, const int* __restrict__ dst,
                                      const int* __restrict__ boff, int* __restrict__ bcur,
                                      unsigned* __restrict__ pairs, int ne, int nb) {
    __shared__ int hist[256], lcur[256], gbase[256];
    const int tid = threadIdx.x;
    hist[tid] = 0; lcur[tid] = 0;
    __syncthreads();
    int e0 = blockIdx.x * SCAT_CH;
    for (int i = tid; i < SCAT_CH; i += 256) {
        int e = e0 + i;
        if (e < ne) atomicAdd(&hist[dst[e] >> 9], 1);
    }
    __syncthreads();
    if (tid < nb) {
        int h = hist[tid];
        gbase[tid] = (h > 0) ? (boff[tid] + atomicAdd(&bcur[tid], h)) : 0;
    }
    __syncthreads();
    for (int i = tid; i < SCAT_CH; i += 256) {
        int e = e0 + i;
        if (e < ne) {
            int d = dst[e];
            int b = d >> 9;
            int r = atomicAdd(&lcur[b], 1);
            pairs[gbase[b] + r] = ((unsigned)(d & 511) << 17) | (unsigned)src[e];
        }
    }
}

// one block per bucket: LDS counting sort -> writes off[] and exact csr[]
__global__ __launch_bounds__(512) void bucket_sort_kernel(
        const unsigned* __restrict__ pairs, const int* __restrict__ boff,
        int* __restrict__ off, int* __restrict__ csr, int n_nodes) {
    __shared__ int cnt[512], lcur[512];
    __shared__ int wt[8];
    const int b = blockIdx.x;
    const int tid = threadIdx.x, lane = tid & 63, wid = tid >> 6;
    const int s = boff[b], t = boff[b + 1];
    cnt[tid] = 0; lcur[tid] = 0;
    __syncthreads();
    for (int i = s + tid; i < t; i += 512)
        atomicAdd(&cnt[pairs[i] >> 17], 1);
    __syncthreads();
    int v = cnt[tid];
    int incl = v;
    #pragma unroll
    for (int o = 1; o < 64; o <<= 1) {
        int tt = __shfl_up(incl, o);
        if (lane >= o) incl += tt;
    }
    if (lane == 63) wt[wid] = incl;
    __syncthreads();
    if (tid < 8) {
        int w = wt[tid], winc = w;
        #pragma unroll
        for (int o = 1; o < 8; o <<= 1) {
            int tt = __shfl_up(winc, o);
            if (tid >= o) winc += tt;
        }
        wt[tid] = winc - w;
    }
    __syncthreads();
    int excl = wt[wid] + incl - v;
    __syncthreads();
    cnt[tid] = excl;     // reuse as exclusive-offset table
    int node = b * 512 + tid;
    if (node < n_nodes) off[node] = s + excl;
    if (b == 0 && tid == 0) off[n_nodes] = boff[gridDim.x];   // = ne
    __syncthreads();
    for (int i = s + tid; i < t; i += 512) {
        unsigned p = pairs[i];
        int bin = p >> 17;
        int r = atomicAdd(&lcur[bin], 1);
        csr[s + cnt[bin] + r] = (int)(p & 0x1FFFFu);
    }
}

// ------------------------------------------------------- weight packs
__global__ void pack_wsplit_kernel(const float* __restrict__ Wl, const float* __restrict__ Wr,
                                   short* __restrict__ Whi, short* __restrict__ Wlo,
                                   int COUT, int K, int CIN) {
    int i = blockIdx.x * blockDim.x + threadIdx.x;
    if (i >= COUT * K) return;
    int n = i / K, k = i % K;
    float v = (k < CIN) ? Wl[n * CIN + k] : Wr[n * CIN + (k - CIN)];
    short h, l;
    splitf(v, h, l);
    Whi[i] = h; Wlo[i] = l;
}

// ---------------------------------- fused layer 1: gather-mean + 10-wide GEMM
__global__ __launch_bounds__(256) void sage1_kernel(
        const float* __restrict__ x, const int* __restrict__ off,
        const int* __restrict__ csr, const float* __restrict__ W1l,
        const float* __restrict__ W1r, const float* __restrict__ b1,
        float* __restrict__ h1, unsigned short* __restrict__ h1b, int n_nodes) {
    __shared__ float sWl[320], sWr[320], sb[64];
    const int tid = threadIdx.x;
    for (int i = tid; i < 320; i += 256) { sWl[i] = W1l[i]; sWr[i] = W1r[i]; }
    if (tid < 64) sb[tid] = b1[tid];
    __syncthreads();
    int node = blockIdx.x * 4 + (tid >> 6);
    int lane = tid & 63;
    if (node >= n_nodes) return;
    int slot = lane >> 3, cg = lane & 7;
    int e0 = off[node], cnt = off[node + 1] - e0;
    float a0 = 0.f, a1 = 0.f;
    int i = slot;
    for (; i + 8 < cnt; i += 16) {
        int s0 = csr[e0 + i];
        int s1 = csr[e0 + i + 8];
        a0 += (cg < 5) ? x[(size_t)s0 * 5 + cg] : 0.f;
        a1 += (cg < 5) ? x[(size_t)s1 * 5 + cg] : 0.f;
    }
    for (; i < cnt; i += 8) {
        int s = csr[e0 + i];
        a0 += (cg < 5) ? x[(size_t)s * 5 + cg] : 0.f;
    }
    float acc = a0 + a1;
    #pragma unroll
    for (int o = 8; o < 64; o <<= 1) acc += __shfl_xor(acc, o);
    float inv = (cnt > 0) ? 1.f / (float)cnt : 0.f;
    float m = acc * inv;
    float xv = (lane < 5) ? x[(size_t)node * 5 + lane] : 0.f;
    float o = sb[lane];
    #pragma unroll
    for (int c = 0; c < 5; ++c) {
        o += sWl[lane * 5 + c] * __shfl(m, c);
        o += sWr[lane * 5 + c] * __shfl(xv, c);
    }
    o = o > 0.f ? o : o * NEG_SLOPE;
    h1[(size_t)node * 64 + lane] = o;
    h1b[(size_t)node * 64 + lane] = f2bf(o);
}

// --------------------------------------- mean aggregation from bf16 mirrors
template<int CIN>
__global__ void agg_bf16_kernel(const unsigned short* __restrict__ hb,
                                const int* __restrict__ off, const int* __restrict__ csr,
                                float* __restrict__ mean, int n_nodes) {
    constexpr int LPR = CIN / 8;
    constexpr int SLOTS = 64 / LPR;
    constexpr int UN = 16 / SLOTS;
    int node = blockIdx.x * (blockDim.x >> 6) + (threadIdx.x >> 6);
    int lane = threadIdx.x & 63;
    if (node >= n_nodes) return;
    int slot = lane / LPR, cg = lane % LPR;
    int e0 = off[node], cnt = off[node + 1] - e0;
    const unsigned short* base = hb + cg * 8;
    float acc[UN][8];
    #pragma unroll
    for (int u = 0; u < UN; ++u)
        #pragma unroll
        for (int k = 0; k < 8; ++k) acc[u][k] = 0.f;
    int i = slot;
    for (; i + (UN - 1) * SLOTS < cnt; i += UN * SLOTS) {
        int s[UN];
        #pragma unroll
        for (int u = 0; u < UN; ++u) s[u] = csr[e0 + i + u * SLOTS];
        uint4 v[UN];
        #pragma unroll
        for (int u = 0; u < UN; ++u)
            v[u] = *(const uint4*)(base + (size_t)s[u] * CIN);
        #pragma unroll
        for (int u = 0; u < UN; ++u) {
            unsigned w0 = v[u].x, w1 = v[u].y, w2 = v[u].z, w3 = v[u].w;
            acc[u][0] += __uint_as_float(w0 << 16);
            acc[u][1] += __uint_as_float(w0 & 0xFFFF0000u);
            acc[u][2] += __uint_as_float(w1 << 16);
            acc[u][3] += __uint_as_float(w1 & 0xFFFF0000u);
            acc[u][4] += __uint_as_float(w2 << 16);
            acc[u][5] += __uint_as_float(w2 & 0xFFFF0000u);
            acc[u][6] += __uint_as_float(w3 << 16);
            acc[u][7] += __uint_as_float(w3 & 0xFFFF0000u);
        }
    }
    for (; i < cnt; i += SLOTS) {
        uint4 v = *(const uint4*)(base + (size_t)csr[e0 + i] * CIN);
        unsigned w0 = v.x, w1 = v.y, w2 = v.z, w3 = v.w;
        acc[0][0] += __uint_as_float(w0 << 16);
        acc[0][1] += __uint_as_float(w0 & 0xFFFF0000u);
        acc[0][2] += __uint_as_float(w1 << 16);
        acc[0][3] += __uint_as_float(w1 & 0xFFFF0000u);
        acc[0][4] += __uint_as_float(w2 << 16);
        acc[0][5] += __uint_as_float(w2 & 0xFFFF0000u);
        acc[0][6] += __uint_as_float(w3 << 16);
        acc[0][7] += __uint_as_float(w3 & 0xFFFF0000u);
    }
    float r[8];
    #pragma unroll
    for (int k = 0; k < 8; ++k) {
        float s = acc[0][k];
        #pragma unroll
        for (int u = 1; u < UN; ++u) s += acc[u][k];
        r[k] = s;
    }
    #pragma unroll
    for (int o = LPR; o < 64; o <<= 1)
        #pragma unroll
        for (int k = 0; k < 8; ++k) r[k] += __shfl_xor(r[k], o);
    if (slot == 0) {
        float inv = (cnt > 0) ? 1.f / (float)cnt : 0.f;
        float4 lo = {r[0] * inv, r[1] * inv, r[2] * inv, r[3] * inv};
        float4 hi = {r[4] * inv, r[5] * inv, r[6] * inv, r[7] * inv};
        float* mp = mean + (size_t)node * CIN + cg * 8;
        *(float4*)mp = lo;
        *(float4*)(mp + 4) = hi;
    }
}

// ------------------------------------------------------------ f32 cat-GEMM (small)
#define BM 128
#define BN 64
#define BK 16

template<bool RELU>
__global__ __launch_bounds__(256) void gemm_cat_kernel(
        const float* __restrict__ AL, const float* __restrict__ AR,
        const float* __restrict__ W, const float* __restrict__ bias,
        float* __restrict__ C, int M, int N, int K, int CIN) {
    __shared__ float As[BK][BM + 4];
    __shared__ float Bs[BK][BN + 4];
    const int row0 = blockIdx.x * BM;
    const int col0 = blockIdx.y * BN;
    const int tid = threadIdx.x;
    const int ttm = tid & 15, ttn = tid >> 4;

    float acc[8][4];
    #pragma unroll
    for (int i = 0; i < 8; ++i)
        #pragma unroll
        for (int j = 0; j < 4; ++j) acc[i][j] = 0.f;

    for (int k0 = 0; k0 < K; k0 += BK) {
        for (int i = tid; i < BM * BK; i += 256) {
            int m = i >> 4, k = i & 15;
            int r = row0 + m, kk = k0 + k;
            float v = 0.f;
            if (r < M && kk < K)
                v = (kk < CIN) ? AL[(size_t)r * CIN + kk]
                               : AR[(size_t)r * CIN + (kk - CIN)];
            As[k][m] = v;
        }
        for (int i = tid; i < BN * BK; i += 256) {
            int n = i >> 4, k = i & 15;
            int c = col0 + n, kk = k0 + k;
            Bs[k][n] = (c < N && kk < K) ? W[(size_t)c * K + kk] : 0.f;
        }
        __syncthreads();
        #pragma unroll
        for (int k = 0; k < BK; ++k) {
            float4 a0 = *(const float4*)&As[k][ttm * 8];
            float4 a1 = *(const float4*)&As[k][ttm * 8 + 4];
            float4 b0 = *(const float4*)&Bs[k][ttn * 4];
            float av[8] = {a0.x, a0.y, a0.z, a0.w, a1.x, a1.y, a1.z, a1.w};
            float bv[4] = {b0.x, b0.y, b0.z, b0.w};
            #pragma unroll
            for (int i = 0; i < 8; ++i)
                #pragma unroll
                for (int j = 0; j < 4; ++j)
                    acc[i][j] += av[i] * bv[j];
        }
        __syncthreads();
    }

    float bv[4];
    #pragma unroll
    for (int j = 0; j < 4; ++j) bv[j] = bias[col0 + ttn * 4 + j];
    #pragma unroll
    for (int i = 0; i < 8; ++i) {
        int r = row0 + ttm * 8 + i;
        if (r < M) {
            float t0 = acc[i][0] + bv[0];
            float t1 = acc[i][1] + bv[1];
            float t2 = acc[i][2] + bv[2];
            float t3 = acc[i][3] + bv[3];
            if (RELU) {
                t0 = t0 > 0.f ? t0 : t0 * NEG_SLOPE;
                t1 = t1 > 0.f ? t1 : t1 * NEG_SLOPE;
                t2 = t2 > 0.f ? t2 : t2 * NEG_SLOPE;
                t3 = t3 > 0.f ? t3 : t3 * NEG_SLOPE;
            }
            float4 v; v.x = t0; v.y = t1; v.z = t2; v.w = t3;
            *(float4*)&C[(size_t)r * N + col0 + ttn * 4] = v;
        }
    }
}

// ------------- split-bf16 MFMA cat-GEMM (N=128/block), register-prefetched
// K, CIN compile-time so the K-loop fully unrolls (reg arrays stay in VGPRs)
template<int K, int CIN>
__global__ __launch_bounds__(256) void gemm_cat_mfma_kernel(
        const float* __restrict__ AL, const float* __restrict__ AR,
        const short* __restrict__ Whi, const short* __restrict__ Wlo,
        const float* __restrict__ bias, float* __restrict__ C,
        unsigned short* __restrict__ Cb16, int M, int N) {
    __shared__ short AsH[128][36], AsL[128][36];
    __shared__ short BsH[128][36], BsL[128][36];
    const int row0 = blockIdx.x * 128;
    const int n0 = blockIdx.y * 128;
    const int tid = threadIdx.x;
    const int w = tid >> 6;
    const int lane31 = tid & 31, lhalf = (tid & 63) >> 5;
    constexpr int NT = K / 32;
    const int arow = tid >> 1, akq = (tid & 1) * 16;
    const int bn = tid & 127, bhalf = tid >> 7;

    f32x16 acc[4];
    #pragma unroll
    for (int ci = 0; ci < 4; ++ci)
        #pragma unroll
        for (int r = 0; r < 16; ++r) acc[ci][r] = 0.f;

    float cvA[16]; uint4 cvB[4];

    auto loadA = [&](int t, float* dst) {
        const int k0 = t * 32;
        const float* Asrc = (k0 < CIN) ? AL : AR;
        const int kb = (k0 < CIN) ? k0 : k0 - CIN;
        #pragma unroll
        for (int i = 0; i < 16; ++i) dst[i] = 0.f;
        int r = row0 + arow;
        if (r < M) {
            const float* p = &Asrc[(size_t)r * CIN + kb + akq];
            #pragma unroll
            for (int q = 0; q < 4; ++q) {
                float4 v = ((const float4*)p)[q];
                dst[q * 4 + 0] = v.x; dst[q * 4 + 1] = v.y;
                dst[q * 4 + 2] = v.z; dst[q * 4 + 3] = v.w;
            }
        }
    };
    auto loadB = [&](int t, uint4* dst) {
        const int k0 = t * 32;
        const short* srcw = bhalf ? Wlo : Whi;
        const uint4* p = (const uint4*)&srcw[(size_t)(n0 + bn) * K + k0];
        #pragma unroll
        for (int q = 0; q < 4; ++q) dst[q] = p[q];
    };

    loadA(0, cvA);
    loadB(0, cvB);

    #pragma unroll
    for (int t = 0; t < NT; ++t) {
        // write phase: split current A regs + store B regs
        #pragma unroll
        for (int half = 0; half < 2; ++half) {
            bh8 h8, l8;
            #pragma unroll
            for (int i = 0; i < 8; ++i) {
                short a, b;
                splitf(cvA[half * 8 + i], a, b);
                h8[i] = a; l8[i] = b;
            }
            *(bh8*)&AsH[arow][akq + half * 8] = h8;
            *(bh8*)&AsL[arow][akq + half * 8] = l8;
        }
        if (bhalf) {
            #pragma unroll
            for (int q = 0; q < 4; ++q) *(uint4*)&BsL[bn][q * 8] = cvB[q];
        } else {
            #pragma unroll
            for (int q = 0; q < 4; ++q) *(uint4*)&BsH[bn][q * 8] = cvB[q];
        }
        __syncthreads();
        float nA[16]; uint4 nB[4];
        if (t + 1 < NT) { loadA(t + 1, nA); loadB(t + 1, nB); }  // prefetch, latency under MFMA
        #pragma unroll
        for (int ks = 0; ks < 2; ++ks) {
            int kofs = ks * 16 + lhalf * 8;
            bh8 aH = *(bh8*)&AsH[w * 32 + lane31][kofs];
            bh8 aL = *(bh8*)&AsL[w * 32 + lane31][kofs];
            #pragma unroll
            for (int ci = 0; ci < 4; ++ci) {
                bh8 bH = *(bh8*)&BsH[ci * 32 + lane31][kofs];
                bh8 bL = *(bh8*)&BsL[ci * 32 + lane31][kofs];
                acc[ci] = __builtin_amdgcn_mfma_f32_32x32x16_bf16(aH, bH, acc[ci], 0, 0, 0);
                acc[ci] = __builtin_amdgcn_mfma_f32_32x32x16_bf16(aH, bL, acc[ci], 0, 0, 0);
                acc[ci] = __builtin_amdgcn_mfma_f32_32x32x16_bf16(aL, bH, acc[ci], 0, 0, 0);
            }
        }
        __syncthreads();
        if (t + 1 < NT) {
            #pragma unroll
            for (int i = 0; i < 16; ++i) cvA[i] = nA[i];
            #pragma unroll
            for (int q = 0; q < 4; ++q) cvB[q] = nB[q];
        }
    }

    #pragma unroll
    for (int ci = 0; ci < 4; ++ci) {
        int col = n0 + ci * 32 + lane31;
        float b = bias[col];
        #pragma unroll
        for (int r = 0; r < 16; ++r) {
            int row = row0 + w * 32 + (r & 3) + 8 * (r >> 2) + 4 * lhalf;
            if (row < M) {
                float v = acc[ci][r] + b;
                v = v > 0.f ? v : v * NEG_SLOPE;
                C[(size_t)row * N + col] = v;
                if (Cb16) Cb16[(size_t)row * N + col] = f2bf(v);
            }
        }
    }
}

// -- split-bf16 MFMA fused layer-3 GEMM + pool, 2 graphs/block, reg-prefetched
template<int CIN>
__global__ __launch_bounds__(512) void gemm_pool_mfma2_kernel(
        const float* __restrict__ AL, const float* __restrict__ AR,
        const short* __restrict__ Whi, const short* __restrict__ Wlo,
        const float* __restrict__ bias, float* __restrict__ gout,
        int npg, int NCH) {
    __shared__ short AsH[128][36], AsL[128][36];
    __shared__ short BsH[256][36], BsL[256][36];
    __shared__ float redS[4][258], redM[4][258];
    const int g2 = blockIdx.x * 2;
    constexpr int K = 2 * CIN;
    constexpr int NT = K / 32;
    const int tid = threadIdx.x;
    const int w = tid >> 6;
    const int lane31 = tid & 31, lhalf = (tid & 63) >> 5;
    const int rt = w & 3, cb = (w >> 2) * 4;
    const int arow = tid >> 2, akq = (tid & 3) * 8;
    const int agrow = arow >> 6, ar = arow & 63;
    const int bn = tid & 255, bhalf = tid >> 8;

    f32x16 acc[4];
    #pragma unroll
    for (int ci = 0; ci < 4; ++ci)
        #pragma unroll
        for (int r = 0; r < 16; ++r) acc[ci][r] = 0.f;

    float cvA[8]; uint4 cvB[4];

    auto loadA = [&](int t, float* dst) {
        const int k0 = t * 32;
        const float* Asrc = (k0 < CIN) ? AL : AR;
        const int kb = (k0 < CIN) ? k0 : k0 - CIN;
        #pragma unroll
        for (int i = 0; i < 8; ++i) dst[i] = 0.f;
        if (ar < npg) {
            const float* p = &Asrc[((size_t)(g2 + agrow) * npg + ar) * CIN + kb + akq];
            #pragma unroll
            for (int q = 0; q < 2; ++q) {
                float4 v = ((const float4*)p)[q];
                dst[q * 4 + 0] = v.x; dst[q * 4 + 1] = v.y;
                dst[q * 4 + 2] = v.z; dst[q * 4 + 3] = v.w;
            }
        }
    };
    auto loadB = [&](int t, uint4* dst) {
        const int k0 = t * 32;
        const short* srcw = bhalf ? Wlo : Whi;
        const uint4* p = (const uint4*)&srcw[(size_t)bn * K + k0];
        #pragma unroll
        for (int q = 0; q < 4; ++q) dst[q] = p[q];
    };

    loadA(0, cvA);
    loadB(0, cvB);

    #pragma unroll
    for (int t = 0; t < NT; ++t) {
        {   // write phase
            bh8 h8, l8;
            #pragma unroll
            for (int i = 0; i < 8; ++i) {
                short a, b;
                splitf(cvA[i], a, b);
                h8[i] = a; l8[i] = b;
            }
            *(bh8*)&AsH[arow][akq] = h8;
            *(bh8*)&AsL[arow][akq] = l8;
            if (bhalf) {
                #pragma unroll
                for (int q = 0; q < 4; ++q) *(uint4*)&BsL[bn][q * 8] = cvB[q];
            } else {
                #pragma unroll
                for (int q = 0; q < 4; ++q) *(uint4*)&BsH[bn][q * 8] = cvB[q];
            }
        }
        __syncthreads();
        float nA[8]; uint4 nB[4];
        if (t + 1 < NT) { loadA(t + 1, nA); loadB(t + 1, nB); }  // prefetch
        #pragma unroll
        for (int ks = 0; ks < 2; ++ks) {
            int kofs = ks * 16 + lhalf * 8;
            bh8 aH = *(bh8*)&AsH[rt * 32 + lane31][kofs];
            bh8 aL = *(bh8*)&AsL[rt * 32 + lane31][kofs];
            #pragma unroll
            for (int ci = 0; ci < 4; ++ci) {
                bh8 bH = *(bh8*)&BsH[(cb + ci) * 32 + lane31][kofs];
                bh8 bL = *(bh8*)&BsL[(cb + ci) * 32 + lane31][kofs];
                acc[ci] = __builtin_amdgcn_mfma_f32_32x32x16_bf16(aH, bH, acc[ci], 0, 0, 0);
                acc[ci] = __builtin_amdgcn_mfma_f32_32x32x16_bf16(aH, bL, acc[ci], 0, 0, 0);
                acc[ci] = __builtin_amdgcn_mfma_f32_32x32x16_bf16(aL, bH, acc[ci], 0, 0, 0);
            }
        }
        __syncthreads();
        if (t + 1 < NT) {
            #pragma unroll
            for (int i = 0; i < 8; ++i) cvA[i] = nA[i];
            #pragma unroll
            for (int q = 0; q < 4; ++q) cvB[q] = nB[q];
        }
    }

    #pragma unroll
    for (int ci = 0; ci < 4; ++ci) {
        int col = (cb + ci) * 32 + lane31;
        float b = bias[col];
        float ls = 0.f, lm = -__builtin_huge_valf();
        #pragma unroll
        for (int r = 0; r < 16; ++r) {
            int crow = (r & 3) + 8 * (r >> 2) + 4 * lhalf;
            int grow = (rt & 1) * 32 + crow;
            if (grow < npg) {
                float v = acc[ci][r] + b;
                v = v > 0.f ? v : v * NEG_SLOPE;
                ls += v;
                lm = fmaxf(lm, v);
            }
        }
        ls += __shfl_xor(ls, 32);
        lm = fmaxf(lm, __shfl_xor(lm, 32));
        if (lhalf == 0) { redS[rt][col] = ls; redM[rt][col] = lm; }
    }
    __syncthreads();
    {
        int c = tid & 255, gi = tid >> 8;
        float s = redS[gi * 2][c] + redS[gi * 2 + 1][c];
        float m = fmaxf(redM[gi * 2][c], redM[gi * 2 + 1][c]);
        gout[(size_t)(g2 + gi) * (2 * NCH) + c] = s / (float)npg;
        gout[(size_t)(g2 + gi) * (2 * NCH) + NCH + c] = m;
    }
}

// ------------------------------------------------------- final 64->1 layer
__global__ void final_kernel(const float* __restrict__ c2, const float* __restrict__ Wc3,
                             const float* __restrict__ bc3, float* __restrict__ out, int G) {
    int g = blockIdx.x * (blockDim.x >> 6) + (threadIdx.x >> 6);
    int lane = threadIdx.x & 63;
    if (g >= G) return;
    float v = c2[(size_t)g * 64 + lane] * Wc3[lane];
    #pragma unroll
    for (int o = 32; o > 0; o >>= 1) v += __shfl_down(v, o);
    if (lane == 0) out[g] = v + bc3[0];
}

// ---------------------------------------------------------------- launcher
extern "C" void kernel_launch(void* const* d_in, const int* in_sizes, int n_in,
                              void* d_out, int out_size, void* d_ws, size_t ws_size,
                              hipStream_t stream) {
    const float* x   = (const float*)d_in[0];
    const int* ei    = (const int*)d_in[1];
    const float* W1l = (const float*)d_in[4];
    const float* b1  = (const float*)d_in[5];
    const float* W1r = (const float*)d_in[6];
    const float* W2l = (const float*)d_in[7];
    const float* b2  = (const float*)d_in[8];
    const float* W2r = (const float*)d_in[9];
    const float* W3l = (const float*)d_in[10];
    const float* b3  = (const float*)d_in[11];
    const float* W3r = (const float*)d_in[12];
    const float* Wc1 = (const float*)d_in[13];
    const float* bc1 = (const float*)d_in[14];
    const float* Wc2 = (const float*)d_in[15];
    const float* bc2 = (const float*)d_in[16];
    const float* Wc3 = (const float*)d_in[17];
    const float* bc3 = (const float*)d_in[18];
    float* out = (float*)d_out;

    const int nodes = in_sizes[0] / 5;      // 100000  (< 2^17 for packed pairs)
    const int ne    = in_sizes[1] / 2;      // 1600000
    const int G     = out_size;             // 2000 (even)
    const int npg   = nodes / G;            // 50
    const int nb    = (nodes + 511) >> 9;   // 196 buckets (<=256)

    char* ws = (char*)d_ws;
    size_t pos = 0;
    auto take = [&](size_t bytes) -> char* {
        char* p = ws + pos;
        pos += (bytes + 255) & ~(size_t)255;
        return p;
    };
    int* off     = (int*)take((size_t)(nodes + 1) * 4);
    int* csr     = (int*)take((size_t)ne * 4);
    int* bcnt    = (int*)take(256 * 4);
    int* bcur    = (int*)take(256 * 4);
    int* boff    = (int*)take(257 * 4);
    short* Whi2  = (short*)take((size_t)128 * 128 * 2);
    short* Wlo2  = (short*)take((size_t)128 * 128 * 2);
    short* Whi3  = (short*)take((size_t)256 * 256 * 2);
    short* Wlo3  = (short*)take((size_t)256 * 256 * 2);
    short* WhiC  = (short*)take((size_t)128 * 512 * 2);
    short* WloC  = (short*)take((size_t)128 * 512 * 2);
    float* gbuf  = (float*)take((size_t)G * 512 * 4);
    float* c1    = (float*)take((size_t)G * 128 * 4);
    float* c2    = (float*)take((size_t)G * 64 * 4);
    // reused region: [mean1 | h1] (51.2MB): pairs during CSR build, mean2 after L2 GEMM
    float* mean1 = (float*)take((size_t)nodes * 64 * 4);
    float* h1    = (float*)take((size_t)nodes * 64 * 4);
    float* h2    = (float*)take((size_t)nodes * 128 * 4);
    // bf16 mirror region R (25.6MB): h1b (12.8MB, dead before h2b written), then h2b
    char* R      = take((size_t)nodes * 128 * 2);
    unsigned short* h1b = (unsigned short*)R;
    unsigned short* h2b = (unsigned short*)R;
    float* mean2 = mean1;               // 51.2MB alias over dead mean1|h1
    unsigned* pairs = (unsigned*)mean1; // 6.4MB alias, dead before mean1 written

    if (pos > ws_size) {
        sentinel_kernel<<<(G + 255) / 256, 256, 0, stream>>>(out, G);
        return;
    }

    const int* src = ei;
    const int* dst = ei + ne;

    hipMemsetAsync(bcnt, 0, 512 * 4, stream);   // bcnt + bcur (adjacent)

    // ---- CSR build v3
    bucket_count_kernel<<<(ne + HIST_CH - 1) / HIST_CH, 256, 0, stream>>>(dst, bcnt, ne, nb);
    scan256_kernel<<<1, 256, 0, stream>>>(bcnt, boff, nb);
    bucket_scatter_kernel<<<(ne + SCAT_CH - 1) / SCAT_CH, 256, 0, stream>>>(
        src, dst, boff, bcur, pairs, ne, nb);
    bucket_sort_kernel<<<nb, 512, 0, stream>>>(pairs, boff, off, csr, nodes);

    pack_wsplit_kernel<<<(128 * 128 + 255) / 256, 256, 0, stream>>>(W2l, W2r, Whi2, Wlo2, 128, 128, 64);
    pack_wsplit_kernel<<<(256 * 256 + 255) / 256, 256, 0, stream>>>(W3l, W3r, Whi3, Wlo3, 256, 256, 128);
    pack_wsplit_kernel<<<(128 * 512 + 255) / 256, 256, 0, stream>>>(Wc1, Wc1, WhiC, WloC, 128, 512, 512);

    // ---- layer 1 fused: h1 = lrelu(W1l·mean(x) + W1r·x + b1), + bf16 mirror
    sage1_kernel<<<(nodes + 3) / 4, 256, 0, stream>>>(x, off, csr, W1l, W1r, b1, h1, h1b, nodes);

    // ---- layer 2: [mean(h1)|h1] (K=128) -> 128  (split-bf16 MFMA, + h2 bf16 mirror)
    agg_bf16_kernel<64><<<(nodes + 3) / 4, 256, 0, stream>>>(h1b, off, csr, mean1, nodes);
    {
        dim3 g((nodes + 127) / 128, 1);
        gemm_cat_mfma_kernel<128, 64><<<g, 256, 0, stream>>>(mean1, h1, Whi2, Wlo2, b2,
                                                             h2, h2b, nodes, 128);
    }
    // ---- layer 3: [mean(h2)|h2] (K=256) -> 256, fused pool (2 graphs/block)
    agg_bf16_kernel<128><<<(nodes + 3) / 4, 256, 0, stream>>>(h2b, off, csr, mean2, nodes);
    gemm_pool_mfma2_kernel<128><<<G / 2, 512, 0, stream>>>(mean2, h2, Whi3, Wlo3, b3, gbuf,
                                                           npg, 256);
    // ---- classifier: 512 -> 128 (MFMA) -> 64 (f32) -> 1
    {
        dim3 g((G + 127) / 128, 1);
        gemm_cat_mfma_kernel<512, 512><<<g, 256, 0, stream>>>(gbuf, gbuf, WhiC, WloC, bc1,
                                                              c1, nullptr, G, 128);
    }
    {
        dim3 g((G + BM - 1) / BM, 64 / BN);
        gemm_cat_kernel<true><<<g, 256, 0, stream>>>(c1, nullptr, Wc2, bc2, c2, G, 64, 128, 128);
    }
    final_kernel<<<(G + 3) / 4, 256, 0, stream>>>(c2, Wc3, bc3, out, G);
}

// Round 12
// 399.311 us; speedup vs baseline: 1.3666x; 1.3666x over previous
//
#include <hip/hip_runtime.h>
#include <cstdint>
#include <cstddef>

#define NEG_SLOPE 0.2f

typedef __attribute__((ext_vector_type(8))) short bh8;     // 8 bf16 in 4 VGPRs
typedef __attribute__((ext_vector_type(16))) float f32x16; // MFMA 32x32 accumulator

// split f32 -> bf16 hi + bf16 lo (x ~= hi + lo, residual ~2^-17 relative)
__device__ inline void splitf(float x, short& hi, short& lo) {
    uint32_t u = __float_as_uint(x);
    uint32_t rh = (u + 0x7FFFu + ((u >> 16) & 1u)) & 0xFFFF0000u;
    hi = (short)(rh >> 16);
    float rem = x - __uint_as_float(rh);
    uint32_t u2 = __float_as_uint(rem);
    lo = (short)((u2 + 0x7FFFu + ((u2 >> 16) & 1u)) >> 16);
}

__device__ inline unsigned short f2bf(float x) {   // round-to-nearest-even bf16
    uint32_t u = __float_as_uint(x);
    return (unsigned short)((u + 0x7FFFu + ((u >> 16) & 1u)) >> 16);
}

// ---------------------------------------------------------------- sentinel
__global__ void sentinel_kernel(float* __restrict__ out, int n) {
    int i = blockIdx.x * blockDim.x + threadIdx.x;
    if (i < n) out[i] = 12345.0f;
}

// ------------------------------------------------- CSR build v3 (bucketed)
// bucket = dst >> 9 (512 nodes); pair = (dst&511)<<17 | src  (needs nodes<2^17)
#define HIST_CH 8192
__global__ void bucket_count_kernel(const int* __restrict__ dst, int* __restrict__ bcnt,
                                    int ne, int nb) {
    __shared__ int hist[256];
    const int tid = threadIdx.x;
    hist[tid] = 0;
    __syncthreads();
    int e0 = blockIdx.x * HIST_CH;
    for (int i = tid; i < HIST_CH; i += 256) {
        int e = e0 + i;
        if (e < ne) atomicAdd(&hist[dst[e] >> 9], 1);
    }
    __syncthreads();
    if (tid < nb && hist[tid] > 0) atomicAdd(&bcnt[tid], hist[tid]);
}

// scan over <=256 bucket counts; boff[0..n], boff[n]=total
__global__ void scan256_kernel(const int* __restrict__ bcnt, int* __restrict__ boff, int n) {
    const int tid = threadIdx.x, lane = tid & 63, wid = tid >> 6;
    __shared__ int wt[4];
    int v = (tid < n) ? bcnt[tid] : 0;
    int incl = v;
    #pragma unroll
    for (int o = 1; o < 64; o <<= 1) {
        int t = __shfl_up(incl, o);
        if (lane >= o) incl += t;
    }
    if (lane == 63) wt[wid] = incl;
    __syncthreads();
    if (tid < 4) {
        int w = wt[tid], winc = w;
        #pragma unroll
        for (int o = 1; o < 4; o <<= 1) {
            int t = __shfl_up(winc, o);
            if (tid >= o) winc += t;
        }
        wt[tid] = winc - w;
    }
    __syncthreads();
    int excl = wt[wid] + incl - v;
    if (tid < n) boff[tid] = excl;
    if (tid == n - 1) boff[n] = excl + v;
}

#define SCAT_CH 4096
__global__ void bucket_scatter_kernel(const int* __restrict__ src, const int* __restrict__ dst,
                                      const int* __restrict__ boff, int* __restrict__ bcur,
                                      unsigned* __restrict__ pairs, int ne, int nb) {
    __shared__ int hist[256], lcur[256], gbase[256];
    const int tid = threadIdx.x;
    hist[tid] = 0; lcur[tid] = 0;
    __syncthreads();
    int e0 = blockIdx.x * SCAT_CH;
    for (int i = tid; i < SCAT_CH; i += 256) {
        int e = e0 + i;
        if (e < ne) atomicAdd(&hist[dst[e] >> 9], 1);
    }
    __syncthreads();
    if (tid < nb) {
        int h = hist[tid];
        gbase[tid] = (h > 0) ? (boff[tid] + atomicAdd(&bcur[tid], h)) : 0;
    }
    __syncthreads();
    for (int i = tid; i < SCAT_CH; i += 256) {
        int e = e0 + i;
        if (e < ne) {
            int d = dst[e];
            int b = d >> 9;
            int r = atomicAdd(&lcur[b], 1);
            pairs[gbase[b] + r] = ((unsigned)(d & 511) << 17) | (unsigned)src[e];
        }
    }
}

// one block per bucket: LDS counting sort -> writes off[] and exact csr[]
__global__ __launch_bounds__(512) void bucket_sort_kernel(
        const unsigned* __restrict__ pairs, const int* __restrict__ boff,
        int* __restrict__ off, int* __restrict__ csr, int n_nodes) {
    __shared__ int cnt[512], lcur[512];
    __shared__ int wt[8];
    const int b = blockIdx.x;
    const int tid = threadIdx.x, lane = tid & 63, wid = tid >> 6;
    const int s = boff[b], t = boff[b + 1];
    cnt[tid] = 0; lcur[tid] = 0;
    __syncthreads();
    for (int i = s + tid; i < t; i += 512)
        atomicAdd(&cnt[pairs[i] >> 17], 1);
    __syncthreads();
    int v = cnt[tid];
    int incl = v;
    #pragma unroll
    for (int o = 1; o < 64; o <<= 1) {
        int tt = __shfl_up(incl, o);
        if (lane >= o) incl += tt;
    }
    if (lane == 63) wt[wid] = incl;
    __syncthreads();
    if (tid < 8) {
        int w = wt[tid], winc = w;
        #pragma unroll
        for (int o = 1; o < 8; o <<= 1) {
            int tt = __shfl_up(winc, o);
            if (tid >= o) winc += tt;
        }
        wt[tid] = winc - w;
    }
    __syncthreads();
    int excl = wt[wid] + incl - v;
    __syncthreads();
    cnt[tid] = excl;     // reuse as exclusive-offset table
    int node = b * 512 + tid;
    if (node < n_nodes) off[node] = s + excl;
    if (b == 0 && tid == 0) off[n_nodes] = boff[gridDim.x];   // = ne
    __syncthreads();
    for (int i = s + tid; i < t; i += 512) {
        unsigned p = pairs[i];
        int bin = p >> 17;
        int r = atomicAdd(&lcur[bin], 1);
        csr[s + cnt[bin] + r] = (int)(p & 0x1FFFFu);
    }
}

// ------------------------------------------------------- weight packs
__global__ void pack_wsplit_kernel(const float* __restrict__ Wl, const float* __restrict__ Wr,
                                   short* __restrict__ Whi, short* __restrict__ Wlo,
                                   int COUT, int K, int CIN) {
    int i = blockIdx.x * blockDim.x + threadIdx.x;
    if (i >= COUT * K) return;
    int n = i / K, k = i % K;
    float v = (k < CIN) ? Wl[n * CIN + k] : Wr[n * CIN + (k - CIN)];
    short h, l;
    splitf(v, h, l);
    Whi[i] = h; Wlo[i] = l;
}

// ---------------------------------- fused layer 1: gather-mean + 10-wide GEMM
__global__ __launch_bounds__(256) void sage1_kernel(
        const float* __restrict__ x, const int* __restrict__ off,
        const int* __restrict__ csr, const float* __restrict__ W1l,
        const float* __restrict__ W1r, const float* __restrict__ b1,
        float* __restrict__ h1, unsigned short* __restrict__ h1b, int n_nodes) {
    __shared__ float sWl[320], sWr[320], sb[64];
    const int tid = threadIdx.x;
    for (int i = tid; i < 320; i += 256) { sWl[i] = W1l[i]; sWr[i] = W1r[i]; }
    if (tid < 64) sb[tid] = b1[tid];
    __syncthreads();
    int node = blockIdx.x * 4 + (tid >> 6);
    int lane = tid & 63;
    if (node >= n_nodes) return;
    int slot = lane >> 3, cg = lane & 7;
    int e0 = off[node], cnt = off[node + 1] - e0;
    float a0 = 0.f, a1 = 0.f;
    int i = slot;
    for (; i + 8 < cnt; i += 16) {
        int s0 = csr[e0 + i];
        int s1 = csr[e0 + i + 8];
        a0 += (cg < 5) ? x[(size_t)s0 * 5 + cg] : 0.f;
        a1 += (cg < 5) ? x[(size_t)s1 * 5 + cg] : 0.f;
    }
    for (; i < cnt; i += 8) {
        int s = csr[e0 + i];
        a0 += (cg < 5) ? x[(size_t)s * 5 + cg] : 0.f;
    }
    float acc = a0 + a1;
    #pragma unroll
    for (int o = 8; o < 64; o <<= 1) acc += __shfl_xor(acc, o);
    float inv = (cnt > 0) ? 1.f / (float)cnt : 0.f;
    float m = acc * inv;
    float xv = (lane < 5) ? x[(size_t)node * 5 + lane] : 0.f;
    float o = sb[lane];
    #pragma unroll
    for (int c = 0; c < 5; ++c) {
        o += sWl[lane * 5 + c] * __shfl(m, c);
        o += sWr[lane * 5 + c] * __shfl(xv, c);
    }
    o = o > 0.f ? o : o * NEG_SLOPE;
    h1[(size_t)node * 64 + lane] = o;
    h1b[(size_t)node * 64 + lane] = f2bf(o);
}

// --------------------------------------- mean aggregation from bf16 mirrors
template<int CIN>
__global__ void agg_bf16_kernel(const unsigned short* __restrict__ hb,
                                const int* __restrict__ off, const int* __restrict__ csr,
                                float* __restrict__ mean, int n_nodes) {
    constexpr int LPR = CIN / 8;
    constexpr int SLOTS = 64 / LPR;
    constexpr int UN = 16 / SLOTS;
    int node = blockIdx.x * (blockDim.x >> 6) + (threadIdx.x >> 6);
    int lane = threadIdx.x & 63;
    if (node >= n_nodes) return;
    int slot = lane / LPR, cg = lane % LPR;
    int e0 = off[node], cnt = off[node + 1] - e0;
    const unsigned short* base = hb + cg * 8;
    float acc[UN][8];
    #pragma unroll
    for (int u = 0; u < UN; ++u)
        #pragma unroll
        for (int k = 0; k < 8; ++k) acc[u][k] = 0.f;
    int i = slot;
    for (; i + (UN - 1) * SLOTS < cnt; i += UN * SLOTS) {
        int s[UN];
        #pragma unroll
        for (int u = 0; u < UN; ++u) s[u] = csr[e0 + i + u * SLOTS];
        uint4 v[UN];
        #pragma unroll
        for (int u = 0; u < UN; ++u)
            v[u] = *(const uint4*)(base + (size_t)s[u] * CIN);
        #pragma unroll
        for (int u = 0; u < UN; ++u) {
            unsigned w0 = v[u].x, w1 = v[u].y, w2 = v[u].z, w3 = v[u].w;
            acc[u][0] += __uint_as_float(w0 << 16);
            acc[u][1] += __uint_as_float(w0 & 0xFFFF0000u);
            acc[u][2] += __uint_as_float(w1 << 16);
            acc[u][3] += __uint_as_float(w1 & 0xFFFF0000u);
            acc[u][4] += __uint_as_float(w2 << 16);
            acc[u][5] += __uint_as_float(w2 & 0xFFFF0000u);
            acc[u][6] += __uint_as_float(w3 << 16);
            acc[u][7] += __uint_as_float(w3 & 0xFFFF0000u);
        }
    }
    for (; i < cnt; i += SLOTS) {
        uint4 v = *(const uint4*)(base + (size_t)csr[e0 + i] * CIN);
        unsigned w0 = v.x, w1 = v.y, w2 = v.z, w3 = v.w;
        acc[0][0] += __uint_as_float(w0 << 16);
        acc[0][1] += __uint_as_float(w0 & 0xFFFF0000u);
        acc[0][2] += __uint_as_float(w1 << 16);
        acc[0][3] += __uint_as_float(w1 & 0xFFFF0000u);
        acc[0][4] += __uint_as_float(w2 << 16);
        acc[0][5] += __uint_as_float(w2 & 0xFFFF0000u);
        acc[0][6] += __uint_as_float(w3 << 16);
        acc[0][7] += __uint_as_float(w3 & 0xFFFF0000u);
    }
    float r[8];
    #pragma unroll
    for (int k = 0; k < 8; ++k) {
        float s = acc[0][k];
        #pragma unroll
        for (int u = 1; u < UN; ++u) s += acc[u][k];
        r[k] = s;
    }
    #pragma unroll
    for (int o = LPR; o < 64; o <<= 1)
        #pragma unroll
        for (int k = 0; k < 8; ++k) r[k] += __shfl_xor(r[k], o);
    if (slot == 0) {
        float inv = (cnt > 0) ? 1.f / (float)cnt : 0.f;
        float4 lo = {r[0] * inv, r[1] * inv, r[2] * inv, r[3] * inv};
        float4 hi = {r[4] * inv, r[5] * inv, r[6] * inv, r[7] * inv};
        float* mp = mean + (size_t)node * CIN + cg * 8;
        *(float4*)mp = lo;
        *(float4*)(mp + 4) = hi;
    }
}

// ------------------------------------------------------------ f32 cat-GEMM (small)
#define BM 128
#define BN 64
#define BK 16

template<bool RELU>
__global__ __launch_bounds__(256) void gemm_cat_kernel(
        const float* __restrict__ AL, const float* __restrict__ AR,
        const float* __restrict__ W, const float* __restrict__ bias,
        float* __restrict__ C, int M, int N, int K, int CIN) {
    __shared__ float As[BK][BM + 4];
    __shared__ float Bs[BK][BN + 4];
    const int row0 = blockIdx.x * BM;
    const int col0 = blockIdx.y * BN;
    const int tid = threadIdx.x;
    const int ttm = tid & 15, ttn = tid >> 4;

    float acc[8][4];
    #pragma unroll
    for (int i = 0; i < 8; ++i)
        #pragma unroll
        for (int j = 0; j < 4; ++j) acc[i][j] = 0.f;

    for (int k0 = 0; k0 < K; k0 += BK) {
        for (int i = tid; i < BM * BK; i += 256) {
            int m = i >> 4, k = i & 15;
            int r = row0 + m, kk = k0 + k;
            float v = 0.f;
            if (r < M && kk < K)
                v = (kk < CIN) ? AL[(size_t)r * CIN + kk]
                               : AR[(size_t)r * CIN + (kk - CIN)];
            As[k][m] = v;
        }
        for (int i = tid; i < BN * BK; i += 256) {
            int n = i >> 4, k = i & 15;
            int c = col0 + n, kk = k0 + k;
            Bs[k][n] = (c < N && kk < K) ? W[(size_t)c * K + kk] : 0.f;
        }
        __syncthreads();
        #pragma unroll
        for (int k = 0; k < BK; ++k) {
            float4 a0 = *(const float4*)&As[k][ttm * 8];
            float4 a1 = *(const float4*)&As[k][ttm * 8 + 4];
            float4 b0 = *(const float4*)&Bs[k][ttn * 4];
            float av[8] = {a0.x, a0.y, a0.z, a0.w, a1.x, a1.y, a1.z, a1.w};
            float bv[4] = {b0.x, b0.y, b0.z, b0.w};
            #pragma unroll
            for (int i = 0; i < 8; ++i)
                #pragma unroll
                for (int j = 0; j < 4; ++j)
                    acc[i][j] += av[i] * bv[j];
        }
        __syncthreads();
    }

    float bv[4];
    #pragma unroll
    for (int j = 0; j < 4; ++j) bv[j] = bias[col0 + ttn * 4 + j];
    #pragma unroll
    for (int i = 0; i < 8; ++i) {
        int r = row0 + ttm * 8 + i;
        if (r < M) {
            float t0 = acc[i][0] + bv[0];
            float t1 = acc[i][1] + bv[1];
            float t2 = acc[i][2] + bv[2];
            float t3 = acc[i][3] + bv[3];
            if (RELU) {
                t0 = t0 > 0.f ? t0 : t0 * NEG_SLOPE;
                t1 = t1 > 0.f ? t1 : t1 * NEG_SLOPE;
                t2 = t2 > 0.f ? t2 : t2 * NEG_SLOPE;
                t3 = t3 > 0.f ? t3 : t3 * NEG_SLOPE;
            }
            float4 v; v.x = t0; v.y = t1; v.z = t2; v.w = t3;
            *(float4*)&C[(size_t)r * N + col0 + ttn * 4] = v;
        }
    }
}

// ------------------------------------- split-bf16 MFMA cat-GEMM (N=128/block)
// (round-10 proven version: no prefetch)
__global__ __launch_bounds__(256) void gemm_cat_mfma_kernel(
        const float* __restrict__ AL, const float* __restrict__ AR,
        const short* __restrict__ Whi, const short* __restrict__ Wlo,
        const float* __restrict__ bias, float* __restrict__ C,
        unsigned short* __restrict__ Cb16,
        int M, int N, int K, int CIN) {
    __shared__ short AsH[128][40], AsL[128][40];
    __shared__ short BsH[128][40], BsL[128][40];
    const int row0 = blockIdx.x * 128;
    const int n0 = blockIdx.y * 128;
    const int tid = threadIdx.x;
    const int w = tid >> 6;
    const int lane31 = tid & 31, lhalf = (tid & 63) >> 5;

    f32x16 acc[4];
    #pragma unroll
    for (int ci = 0; ci < 4; ++ci)
        #pragma unroll
        for (int r = 0; r < 16; ++r) acc[ci][r] = 0.f;

    for (int k0 = 0; k0 < K; k0 += 32) {
        const float* Asrc = (k0 < CIN) ? AL : AR;
        const int kb = (k0 < CIN) ? k0 : k0 - CIN;
        {
            int row = tid >> 1, kq = (tid & 1) * 16;
            int r = row0 + row;
            float vv[16];
            #pragma unroll
            for (int i = 0; i < 16; ++i) vv[i] = 0.f;
            if (r < M) {
                const float* p = &Asrc[(size_t)r * CIN + kb + kq];
                #pragma unroll
                for (int q = 0; q < 4; ++q) {
                    float4 v = ((const float4*)p)[q];
                    vv[q * 4 + 0] = v.x; vv[q * 4 + 1] = v.y;
                    vv[q * 4 + 2] = v.z; vv[q * 4 + 3] = v.w;
                }
            }
            #pragma unroll
            for (int half = 0; half < 2; ++half) {
                bh8 h8, l8;
                #pragma unroll
                for (int i = 0; i < 8; ++i) {
                    short a, b;
                    splitf(vv[half * 8 + i], a, b);
                    h8[i] = a; l8[i] = b;
                }
                *(bh8*)&AsH[row][kq + half * 8] = h8;
                *(bh8*)&AsL[row][kq + half * 8] = l8;
            }
        }
        {
            int n = tid & 127, half = tid >> 7;
            const short* src = half ? Wlo : Whi;
            const uint4* p = (const uint4*)&src[(size_t)(n0 + n) * K + k0];
            if (half) {
                #pragma unroll
                for (int q = 0; q < 4; ++q) *(uint4*)&BsL[n][q * 8] = p[q];
            } else {
                #pragma unroll
                for (int q = 0; q < 4; ++q) *(uint4*)&BsH[n][q * 8] = p[q];
            }
        }
        __syncthreads();
        #pragma unroll
        for (int ks = 0; ks < 2; ++ks) {
            int kofs = ks * 16 + lhalf * 8;
            bh8 aH = *(bh8*)&AsH[w * 32 + lane31][kofs];
            bh8 aL = *(bh8*)&AsL[w * 32 + lane31][kofs];
            #pragma unroll
            for (int ci = 0; ci < 4; ++ci) {
                bh8 bH = *(bh8*)&BsH[ci * 32 + lane31][kofs];
                bh8 bL = *(bh8*)&BsL[ci * 32 + lane31][kofs];
                acc[ci] = __builtin_amdgcn_mfma_f32_32x32x16_bf16(aH, bH, acc[ci], 0, 0, 0);
                acc[ci] = __builtin_amdgcn_mfma_f32_32x32x16_bf16(aH, bL, acc[ci], 0, 0, 0);
                acc[ci] = __builtin_amdgcn_mfma_f32_32x32x16_bf16(aL, bH, acc[ci], 0, 0, 0);
            }
        }
        __syncthreads();
    }

    #pragma unroll
    for (int ci = 0; ci < 4; ++ci) {
        int col = n0 + ci * 32 + lane31;
        float b = bias[col];
        #pragma unroll
        for (int r = 0; r < 16; ++r) {
            int row = row0 + w * 32 + (r & 3) + 8 * (r >> 2) + 4 * lhalf;
            if (row < M) {
                float v = acc[ci][r] + b;
                v = v > 0.f ? v : v * NEG_SLOPE;
                C[(size_t)row * N + col] = v;
                if (Cb16) Cb16[(size_t)row * N + col] = f2bf(v);
            }
        }
    }
}

// ---- split-bf16 MFMA fused layer-3 GEMM + pool, 2 graphs/block,
//      register prefetch with NAMED registers only (no arrays/pointer-outs)
template<int CIN>
__global__ __launch_bounds__(512) void gemm_pool_mfma2_kernel(
        const float* __restrict__ AL, const float* __restrict__ AR,
        const short* __restrict__ Whi, const short* __restrict__ Wlo,
        const float* __restrict__ bias, float* __restrict__ gout,
        int npg, int NCH) {
    __shared__ short AsH[128][40], AsL[128][40];
    __shared__ short BsH[256][40], BsL[256][40];
    __shared__ float redS[4][258], redM[4][258];
    const int g2 = blockIdx.x * 2;
    constexpr int K = 2 * CIN;
    constexpr int NT = K / 32;
    const int tid = threadIdx.x;
    const int w = tid >> 6;
    const int lane31 = tid & 31, lhalf = (tid & 63) >> 5;
    const int rt = w & 3, cb = (w >> 2) * 4;
    const int arow = tid >> 2, akq = (tid & 3) * 8;
    const int agrow = arow >> 6, ar = arow & 63;
    const int bn = tid & 255, bhalf = tid >> 8;

    f32x16 acc[4];
    #pragma unroll
    for (int ci = 0; ci < 4; ++ci)
        #pragma unroll
        for (int r = 0; r < 16; ++r) acc[ci][r] = 0.f;

    const size_t abase = ((size_t)(g2 + agrow) * npg + ar) * CIN + akq;
    const short* srcw = bhalf ? Wlo : Whi;

    float4 cA0 = {0.f,0.f,0.f,0.f}, cA1 = {0.f,0.f,0.f,0.f};
    uint4 cB0, cB1, cB2, cB3;
    {   // tile 0 loads (k0 = 0 < CIN always)
        if (ar < npg) {
            const float4* p = (const float4*)&AL[abase];
            cA0 = p[0]; cA1 = p[1];
        }
        const uint4* pb = (const uint4*)&srcw[(size_t)bn * K];
        cB0 = pb[0]; cB1 = pb[1]; cB2 = pb[2]; cB3 = pb[3];
    }

    #pragma unroll
    for (int t = 0; t < NT; ++t) {
        {   // write phase: split current A regs, store current B regs
            bh8 h8, l8; short a, b;
            splitf(cA0.x, a, b); h8[0] = a; l8[0] = b;
            splitf(cA0.y, a, b); h8[1] = a; l8[1] = b;
            splitf(cA0.z, a, b); h8[2] = a; l8[2] = b;
            splitf(cA0.w, a, b); h8[3] = a; l8[3] = b;
            splitf(cA1.x, a, b); h8[4] = a; l8[4] = b;
            splitf(cA1.y, a, b); h8[5] = a; l8[5] = b;
            splitf(cA1.z, a, b); h8[6] = a; l8[6] = b;
            splitf(cA1.w, a, b); h8[7] = a; l8[7] = b;
            *(bh8*)&AsH[arow][akq] = h8;
            *(bh8*)&AsL[arow][akq] = l8;
            if (bhalf) {
                *(uint4*)&BsL[bn][0]  = cB0; *(uint4*)&BsL[bn][8]  = cB1;
                *(uint4*)&BsL[bn][16] = cB2; *(uint4*)&BsL[bn][24] = cB3;
            } else {
                *(uint4*)&BsH[bn][0]  = cB0; *(uint4*)&BsH[bn][8]  = cB1;
                *(uint4*)&BsH[bn][16] = cB2; *(uint4*)&BsH[bn][24] = cB3;
            }
        }
        __syncthreads();
        // prefetch tile t+1 into NAMED regs; latency hides under MFMA below
        float4 nA0 = {0.f,0.f,0.f,0.f}, nA1 = {0.f,0.f,0.f,0.f};
        uint4 nB0 = {0,0,0,0}, nB1 = {0,0,0,0}, nB2 = {0,0,0,0}, nB3 = {0,0,0,0};
        if (t + 1 < NT) {
            const int k0 = (t + 1) * 32;
            const float* Asrc = (k0 < CIN) ? AL : AR;
            const int kb = (k0 < CIN) ? k0 : k0 - CIN;
            if (ar < npg) {
                const float4* p = (const float4*)&Asrc[abase + kb - akq + akq]; // = abase + kb
                p = (const float4*)&Asrc[abase + kb];
                nA0 = p[0]; nA1 = p[1];
            }
            const uint4* pb = (const uint4*)&srcw[(size_t)bn * K + k0];
            nB0 = pb[0]; nB1 = pb[1]; nB2 = pb[2]; nB3 = pb[3];
        }
        #pragma unroll
        for (int ks = 0; ks < 2; ++ks) {
            int kofs = ks * 16 + lhalf * 8;
            bh8 aH = *(bh8*)&AsH[rt * 32 + lane31][kofs];
            bh8 aL = *(bh8*)&AsL[rt * 32 + lane31][kofs];
            #pragma unroll
            for (int ci = 0; ci < 4; ++ci) {
                bh8 bH = *(bh8*)&BsH[(cb + ci) * 32 + lane31][kofs];
                bh8 bL = *(bh8*)&BsL[(cb + ci) * 32 + lane31][kofs];
                acc[ci] = __builtin_amdgcn_mfma_f32_32x32x16_bf16(aH, bH, acc[ci], 0, 0, 0);
                acc[ci] = __builtin_amdgcn_mfma_f32_32x32x16_bf16(aH, bL, acc[ci], 0, 0, 0);
                acc[ci] = __builtin_amdgcn_mfma_f32_32x32x16_bf16(aL, bH, acc[ci], 0, 0, 0);
            }
        }
        __syncthreads();
        if (t + 1 < NT) {
            cA0 = nA0; cA1 = nA1;
            cB0 = nB0; cB1 = nB1; cB2 = nB2; cB3 = nB3;
        }
    }

    #pragma unroll
    for (int ci = 0; ci < 4; ++ci) {
        int col = (cb + ci) * 32 + lane31;
        float b = bias[col];
        float ls = 0.f, lm = -__builtin_huge_valf();
        #pragma unroll
        for (int r = 0; r < 16; ++r) {
            int crow = (r & 3) + 8 * (r >> 2) + 4 * lhalf;
            int grow = (rt & 1) * 32 + crow;
            if (grow < npg) {
                float v = acc[ci][r] + b;
                v = v > 0.f ? v : v * NEG_SLOPE;
                ls += v;
                lm = fmaxf(lm, v);
            }
        }
        ls += __shfl_xor(ls, 32);
        lm = fmaxf(lm, __shfl_xor(lm, 32));
        if (lhalf == 0) { redS[rt][col] = ls; redM[rt][col] = lm; }
    }
    __syncthreads();
    {
        int c = tid & 255, gi = tid >> 8;
        float s = redS[gi * 2][c] + redS[gi * 2 + 1][c];
        float m = fmaxf(redM[gi * 2][c], redM[gi * 2 + 1][c]);
        gout[(size_t)(g2 + gi) * (2 * NCH) + c] = s / (float)npg;
        gout[(size_t)(g2 + gi) * (2 * NCH) + NCH + c] = m;
    }
}

// ------------------------------------------------------- final 64->1 layer
__global__ void final_kernel(const float* __restrict__ c2, const float* __restrict__ Wc3,
                             const float* __restrict__ bc3, float* __restrict__ out, int G) {
    int g = blockIdx.x * (blockDim.x >> 6) + (threadIdx.x >> 6);
    int lane = threadIdx.x & 63;
    if (g >= G) return;
    float v = c2[(size_t)g * 64 + lane] * Wc3[lane];
    #pragma unroll
    for (int o = 32; o > 0; o >>= 1) v += __shfl_down(v, o);
    if (lane == 0) out[g] = v + bc3[0];
}

// ---------------------------------------------------------------- launcher
extern "C" void kernel_launch(void* const* d_in, const int* in_sizes, int n_in,
                              void* d_out, int out_size, void* d_ws, size_t ws_size,
                              hipStream_t stream) {
    const float* x   = (const float*)d_in[0];
    const int* ei    = (const int*)d_in[1];
    const float* W1l = (const float*)d_in[4];
    const float* b1  = (const float*)d_in[5];
    const float* W1r = (const float*)d_in[6];
    const float* W2l = (const float*)d_in[7];
    const float* b2  = (const float*)d_in[8];
    const float* W2r = (const float*)d_in[9];
    const float* W3l = (const float*)d_in[10];
    const float* b3  = (const float*)d_in[11];
    const float* W3r = (const float*)d_in[12];
    const float* Wc1 = (const float*)d_in[13];
    const float* bc1 = (const float*)d_in[14];
    const float* Wc2 = (const float*)d_in[15];
    const float* bc2 = (const float*)d_in[16];
    const float* Wc3 = (const float*)d_in[17];
    const float* bc3 = (const float*)d_in[18];
    float* out = (float*)d_out;

    const int nodes = in_sizes[0] / 5;      // 100000  (< 2^17 for packed pairs)
    const int ne    = in_sizes[1] / 2;      // 1600000
    const int G     = out_size;             // 2000 (even)
    const int npg   = nodes / G;            // 50
    const int nb    = (nodes + 511) >> 9;   // 196 buckets (<=256)

    char* ws = (char*)d_ws;
    size_t pos = 0;
    auto take = [&](size_t bytes) -> char* {
        char* p = ws + pos;
        pos += (bytes + 255) & ~(size_t)255;
        return p;
    };
    int* off     = (int*)take((size_t)(nodes + 1) * 4);
    int* csr     = (int*)take((size_t)ne * 4);
    int* bcnt    = (int*)take(256 * 4);
    int* bcur    = (int*)take(256 * 4);
    int* boff    = (int*)take(257 * 4);
    short* Whi2  = (short*)take((size_t)128 * 128 * 2);
    short* Wlo2  = (short*)take((size_t)128 * 128 * 2);
    short* Whi3  = (short*)take((size_t)256 * 256 * 2);
    short* Wlo3  = (short*)take((size_t)256 * 256 * 2);
    short* WhiC  = (short*)take((size_t)128 * 512 * 2);
    short* WloC  = (short*)take((size_t)128 * 512 * 2);
    float* gbuf  = (float*)take((size_t)G * 512 * 4);
    float* c1    = (float*)take((size_t)G * 128 * 4);
    float* c2    = (float*)take((size_t)G * 64 * 4);
    // reused region: [mean1 | h1] (51.2MB): pairs during CSR build, mean2 after L2 GEMM
    float* mean1 = (float*)take((size_t)nodes * 64 * 4);
    float* h1    = (float*)take((size_t)nodes * 64 * 4);
    float* h2    = (float*)take((size_t)nodes * 128 * 4);
    // bf16 mirror region R (25.6MB): h1b (12.8MB, dead before h2b written), then h2b
    char* R      = take((size_t)nodes * 128 * 2);
    unsigned short* h1b = (unsigned short*)R;
    unsigned short* h2b = (unsigned short*)R;
    float* mean2 = mean1;               // 51.2MB alias over dead mean1|h1
    unsigned* pairs = (unsigned*)mean1; // 6.4MB alias, dead before mean1 written

    if (pos > ws_size) {
        sentinel_kernel<<<(G + 255) / 256, 256, 0, stream>>>(out, G);
        return;
    }

    const int* src = ei;
    const int* dst = ei + ne;

    hipMemsetAsync(bcnt, 0, 512 * 4, stream);   // bcnt + bcur (adjacent)

    // ---- CSR build v3
    bucket_count_kernel<<<(ne + HIST_CH - 1) / HIST_CH, 256, 0, stream>>>(dst, bcnt, ne, nb);
    scan256_kernel<<<1, 256, 0, stream>>>(bcnt, boff, nb);
    bucket_scatter_kernel<<<(ne + SCAT_CH - 1) / SCAT_CH, 256, 0, stream>>>(
        src, dst, boff, bcur, pairs, ne, nb);
    bucket_sort_kernel<<<nb, 512, 0, stream>>>(pairs, boff, off, csr, nodes);

    pack_wsplit_kernel<<<(128 * 128 + 255) / 256, 256, 0, stream>>>(W2l, W2r, Whi2, Wlo2, 128, 128, 64);
    pack_wsplit_kernel<<<(256 * 256 + 255) / 256, 256, 0, stream>>>(W3l, W3r, Whi3, Wlo3, 256, 256, 128);
    pack_wsplit_kernel<<<(128 * 512 + 255) / 256, 256, 0, stream>>>(Wc1, Wc1, WhiC, WloC, 128, 512, 512);

    // ---- layer 1 fused: h1 = lrelu(W1l·mean(x) + W1r·x + b1), + bf16 mirror
    sage1_kernel<<<(nodes + 3) / 4, 256, 0, stream>>>(x, off, csr, W1l, W1r, b1, h1, h1b, nodes);

    // ---- layer 2: [mean(h1)|h1] (K=128) -> 128  (split-bf16 MFMA, + h2 bf16 mirror)
    agg_bf16_kernel<64><<<(nodes + 3) / 4, 256, 0, stream>>>(h1b, off, csr, mean1, nodes);
    {
        dim3 g((nodes + 127) / 128, 1);
        gemm_cat_mfma_kernel<<<g, 256, 0, stream>>>(mean1, h1, Whi2, Wlo2, b2, h2, h2b,
                                                    nodes, 128, 128, 64);
    }
    // ---- layer 3: [mean(h2)|h2] (K=256) -> 256, fused pool (2 graphs/block)
    agg_bf16_kernel<128><<<(nodes + 3) / 4, 256, 0, stream>>>(h2b, off, csr, mean2, nodes);
    gemm_pool_mfma2_kernel<128><<<G / 2, 512, 0, stream>>>(mean2, h2, Whi3, Wlo3, b3, gbuf,
                                                           npg, 256);
    // ---- classifier: 512 -> 128 (MFMA) -> 64 (f32) -> 1
    {
        dim3 g((G + 127) / 128, 1);
        gemm_cat_mfma_kernel<<<g, 256, 0, stream>>>(gbuf, gbuf, WhiC, WloC, bc1, c1, nullptr,
                                                    G, 128, 512, 512);
    }
    {
        dim3 g((G + BM - 1) / BM, 64 / BN);
        gemm_cat_kernel<true><<<g, 256, 0, stream>>>(c1, nullptr, Wc2, bc2, c2, G, 64, 128, 128);
    }
    final_kernel<<<(G + 3) / 4, 256, 0, stream>>>(c2, Wc3, bc3, out, G);
}

// Round 13
// 395.232 us; speedup vs baseline: 1.3807x; 1.0103x over previous
//
#include <hip/hip_runtime.h>
#include <cstdint>
#include <cstddef>

#define NEG_SLOPE 0.2f

typedef __attribute__((ext_vector_type(8))) short bh8;     // 8 bf16 in 4 VGPRs
typedef __attribute__((ext_vector_type(16))) float f32x16; // MFMA 32x32 accumulator

// split f32 -> bf16 hi + bf16 lo (x ~= hi + lo, residual ~2^-17 relative)
__device__ inline void splitf(float x, short& hi, short& lo) {
    uint32_t u = __float_as_uint(x);
    uint32_t rh = (u + 0x7FFFu + ((u >> 16) & 1u)) & 0xFFFF0000u;
    hi = (short)(rh >> 16);
    float rem = x - __uint_as_float(rh);
    uint32_t u2 = __float_as_uint(rem);
    lo = (short)((u2 + 0x7FFFu + ((u2 >> 16) & 1u)) >> 16);
}

// ---------------------------------------------------------------- sentinel
__global__ void sentinel_kernel(float* __restrict__ out, int n) {
    int i = blockIdx.x * blockDim.x + threadIdx.x;
    if (i < n) out[i] = 12345.0f;
}

// ------------------------------------------------- CSR build v3 (bucketed)
#define HIST_CH 8192
__global__ void bucket_count_kernel(const int* __restrict__ dst, int* __restrict__ bcnt,
                                    int ne, int nb) {
    __shared__ int hist[256];
    const int tid = threadIdx.x;
    hist[tid] = 0;
    __syncthreads();
    int e0 = blockIdx.x * HIST_CH;
    for (int i = tid; i < HIST_CH; i += 256) {
        int e = e0 + i;
        if (e < ne) atomicAdd(&hist[dst[e] >> 9], 1);
    }
    __syncthreads();
    if (tid < nb && hist[tid] > 0) atomicAdd(&bcnt[tid], hist[tid]);
}

__global__ void scan256_kernel(const int* __restrict__ bcnt, int* __restrict__ boff, int n) {
    const int tid = threadIdx.x, lane = tid & 63, wid = tid >> 6;
    __shared__ int wt[4];
    int v = (tid < n) ? bcnt[tid] : 0;
    int incl = v;
    #pragma unroll
    for (int o = 1; o < 64; o <<= 1) {
        int t = __shfl_up(incl, o);
        if (lane >= o) incl += t;
    }
    if (lane == 63) wt[wid] = incl;
    __syncthreads();
    if (tid < 4) {
        int w = wt[tid], winc = w;
        #pragma unroll
        for (int o = 1; o < 4; o <<= 1) {
            int t = __shfl_up(winc, o);
            if (tid >= o) winc += t;
        }
        wt[tid] = winc - w;
    }
    __syncthreads();
    int excl = wt[wid] + incl - v;
    if (tid < n) boff[tid] = excl;
    if (tid == n - 1) boff[n] = excl + v;
}

#define SCAT_CH 4096
__global__ void bucket_scatter_kernel(const int* __restrict__ src, const int* __restrict__ dst,
                                      const int* __restrict__ boff, int* __restrict__ bcur,
                                      unsigned* __restrict__ pairs, int ne, int nb) {
    __shared__ int hist[256], lcur[256], gbase[256];
    const int tid = threadIdx.x;
    hist[tid] = 0; lcur[tid] = 0;
    __syncthreads();
    int e0 = blockIdx.x * SCAT_CH;
    for (int i = tid; i < SCAT_CH; i += 256) {
        int e = e0 + i;
        if (e < ne) atomicAdd(&hist[dst[e] >> 9], 1);
    }
    __syncthreads();
    if (tid < nb) {
        int h = hist[tid];
        gbase[tid] = (h > 0) ? (boff[tid] + atomicAdd(&bcur[tid], h)) : 0;
    }
    __syncthreads();
    for (int i = tid; i < SCAT_CH; i += 256) {
        int e = e0 + i;
        if (e < ne) {
            int d = dst[e];
            int b = d >> 9;
            int r = atomicAdd(&lcur[b], 1);
            pairs[gbase[b] + r] = ((unsigned)(d & 511) << 17) | (unsigned)src[e];
        }
    }
}

__global__ __launch_bounds__(512) void bucket_sort_kernel(
        const unsigned* __restrict__ pairs, const int* __restrict__ boff,
        int* __restrict__ off, int* __restrict__ csr, int n_nodes) {
    __shared__ int cnt[512], lcur[512];
    __shared__ int wt[8];
    const int b = blockIdx.x;
    const int tid = threadIdx.x, lane = tid & 63, wid = tid >> 6;
    const int s = boff[b], t = boff[b + 1];
    cnt[tid] = 0; lcur[tid] = 0;
    __syncthreads();
    for (int i = s + tid; i < t; i += 512)
        atomicAdd(&cnt[pairs[i] >> 17], 1);
    __syncthreads();
    int v = cnt[tid];
    int incl = v;
    #pragma unroll
    for (int o = 1; o < 64; o <<= 1) {
        int tt = __shfl_up(incl, o);
        if (lane >= o) incl += tt;
    }
    if (lane == 63) wt[wid] = incl;
    __syncthreads();
    if (tid < 8) {
        int w = wt[tid], winc = w;
        #pragma unroll
        for (int o = 1; o < 8; o <<= 1) {
            int tt = __shfl_up(winc, o);
            if (tid >= o) winc += tt;
        }
        wt[tid] = winc - w;
    }
    __syncthreads();
    int excl = wt[wid] + incl - v;
    __syncthreads();
    cnt[tid] = excl;
    int node = b * 512 + tid;
    if (node < n_nodes) off[node] = s + excl;
    if (b == 0 && tid == 0) off[n_nodes] = boff[gridDim.x];
    __syncthreads();
    for (int i = s + tid; i < t; i += 512) {
        unsigned p = pairs[i];
        int bin = p >> 17;
        int r = atomicAdd(&lcur[bin], 1);
        csr[s + cnt[bin] + r] = (int)(p & 0x1FFFFu);
    }
}

// ------------------------------------------------------- weight packs
__global__ void pack_wsplit_kernel(const float* __restrict__ Wl, const float* __restrict__ Wr,
                                   short* __restrict__ Whi, short* __restrict__ Wlo,
                                   int COUT, int K, int CIN) {
    int i = blockIdx.x * blockDim.x + threadIdx.x;
    if (i >= COUT * K) return;
    int n = i / K, k = i % K;
    float v = (k < CIN) ? Wl[n * CIN + k] : Wr[n * CIN + (k - CIN)];
    short h, l;
    splitf(v, h, l);
    Whi[i] = h; Wlo[i] = l;
}

// ---------------------------------- fused layer 1: gather-mean + 10-wide GEMM
// writes h1 pre-split as (hi, lo) bf16 pair; gathers read hi (== rne bf16)
__global__ __launch_bounds__(256) void sage1_kernel(
        const float* __restrict__ x, const int* __restrict__ off,
        const int* __restrict__ csr, const float* __restrict__ W1l,
        const float* __restrict__ W1r, const float* __restrict__ b1,
        unsigned short* __restrict__ h1hi, unsigned short* __restrict__ h1lo,
        int n_nodes) {
    __shared__ float sWl[320], sWr[320], sb[64];
    const int tid = threadIdx.x;
    for (int i = tid; i < 320; i += 256) { sWl[i] = W1l[i]; sWr[i] = W1r[i]; }
    if (tid < 64) sb[tid] = b1[tid];
    __syncthreads();
    int node = blockIdx.x * 4 + (tid >> 6);
    int lane = tid & 63;
    if (node >= n_nodes) return;
    int slot = lane >> 3, cg = lane & 7;
    int e0 = off[node], cnt = off[node + 1] - e0;
    float a0 = 0.f, a1 = 0.f;
    int i = slot;
    for (; i + 8 < cnt; i += 16) {
        int s0 = csr[e0 + i];
        int s1 = csr[e0 + i + 8];
        a0 += (cg < 5) ? x[(size_t)s0 * 5 + cg] : 0.f;
        a1 += (cg < 5) ? x[(size_t)s1 * 5 + cg] : 0.f;
    }
    for (; i < cnt; i += 8) {
        int s = csr[e0 + i];
        a0 += (cg < 5) ? x[(size_t)s * 5 + cg] : 0.f;
    }
    float acc = a0 + a1;
    #pragma unroll
    for (int o = 8; o < 64; o <<= 1) acc += __shfl_xor(acc, o);
    float inv = (cnt > 0) ? 1.f / (float)cnt : 0.f;
    float m = acc * inv;
    float xv = (lane < 5) ? x[(size_t)node * 5 + lane] : 0.f;
    float o = sb[lane];
    #pragma unroll
    for (int c = 0; c < 5; ++c) {
        o += sWl[lane * 5 + c] * __shfl(m, c);
        o += sWr[lane * 5 + c] * __shfl(xv, c);
    }
    o = o > 0.f ? o : o * NEG_SLOPE;
    short h, l;
    splitf(o, h, l);
    h1hi[(size_t)node * 64 + lane] = (unsigned short)h;
    h1lo[(size_t)node * 64 + lane] = (unsigned short)l;
}

// --------------------------------------- mean aggregation from bf16-hi mirrors
// output mean pre-split as (hi, lo) bf16 pair
template<int CIN>
__global__ void agg_bf16_kernel(const unsigned short* __restrict__ hb,
                                const int* __restrict__ off, const int* __restrict__ csr,
                                unsigned short* __restrict__ mhi,
                                unsigned short* __restrict__ mlo, int n_nodes) {
    constexpr int LPR = CIN / 8;
    constexpr int SLOTS = 64 / LPR;
    constexpr int UN = 16 / SLOTS;
    int node = blockIdx.x * (blockDim.x >> 6) + (threadIdx.x >> 6);
    int lane = threadIdx.x & 63;
    if (node >= n_nodes) return;
    int slot = lane / LPR, cg = lane % LPR;
    int e0 = off[node], cnt = off[node + 1] - e0;
    const unsigned short* base = hb + cg * 8;
    float acc[UN][8];
    #pragma unroll
    for (int u = 0; u < UN; ++u)
        #pragma unroll
        for (int k = 0; k < 8; ++k) acc[u][k] = 0.f;
    int i = slot;
    for (; i + (UN - 1) * SLOTS < cnt; i += UN * SLOTS) {
        int s[UN];
        #pragma unroll
        for (int u = 0; u < UN; ++u) s[u] = csr[e0 + i + u * SLOTS];
        uint4 v[UN];
        #pragma unroll
        for (int u = 0; u < UN; ++u)
            v[u] = *(const uint4*)(base + (size_t)s[u] * CIN);
        #pragma unroll
        for (int u = 0; u < UN; ++u) {
            unsigned w0 = v[u].x, w1 = v[u].y, w2 = v[u].z, w3 = v[u].w;
            acc[u][0] += __uint_as_float(w0 << 16);
            acc[u][1] += __uint_as_float(w0 & 0xFFFF0000u);
            acc[u][2] += __uint_as_float(w1 << 16);
            acc[u][3] += __uint_as_float(w1 & 0xFFFF0000u);
            acc[u][4] += __uint_as_float(w2 << 16);
            acc[u][5] += __uint_as_float(w2 & 0xFFFF0000u);
            acc[u][6] += __uint_as_float(w3 << 16);
            acc[u][7] += __uint_as_float(w3 & 0xFFFF0000u);
        }
    }
    for (; i < cnt; i += SLOTS) {
        uint4 v = *(const uint4*)(base + (size_t)csr[e0 + i] * CIN);
        unsigned w0 = v.x, w1 = v.y, w2 = v.z, w3 = v.w;
        acc[0][0] += __uint_as_float(w0 << 16);
        acc[0][1] += __uint_as_float(w0 & 0xFFFF0000u);
        acc[0][2] += __uint_as_float(w1 << 16);
        acc[0][3] += __uint_as_float(w1 & 0xFFFF0000u);
        acc[0][4] += __uint_as_float(w2 << 16);
        acc[0][5] += __uint_as_float(w2 & 0xFFFF0000u);
        acc[0][6] += __uint_as_float(w3 << 16);
        acc[0][7] += __uint_as_float(w3 & 0xFFFF0000u);
    }
    float r[8];
    #pragma unroll
    for (int k = 0; k < 8; ++k) {
        float s = acc[0][k];
        #pragma unroll
        for (int u = 1; u < UN; ++u) s += acc[u][k];
        r[k] = s;
    }
    #pragma unroll
    for (int o = LPR; o < 64; o <<= 1)
        #pragma unroll
        for (int k = 0; k < 8; ++k) r[k] += __shfl_xor(r[k], o);
    if (slot == 0) {
        float inv = (cnt > 0) ? 1.f / (float)cnt : 0.f;
        bh8 ho, lo8;
        #pragma unroll
        for (int k = 0; k < 8; ++k) {
            short a, b;
            splitf(r[k] * inv, a, b);
            ho[k] = a; lo8[k] = b;
        }
        size_t idx = (size_t)node * CIN + cg * 8;
        *(bh8*)&mhi[idx] = ho;
        *(bh8*)&mlo[idx] = lo8;
    }
}

// ------------------------------------------------------------ f32 cat-GEMM (small)
#define BM 128
#define BN 64
#define BK 16

template<bool RELU>
__global__ __launch_bounds__(256) void gemm_cat_kernel(
        const float* __restrict__ AL, const float* __restrict__ AR,
        const float* __restrict__ W, const float* __restrict__ bias,
        float* __restrict__ C, int M, int N, int K, int CIN) {
    __shared__ float As[BK][BM + 4];
    __shared__ float Bs[BK][BN + 4];
    const int row0 = blockIdx.x * BM;
    const int col0 = blockIdx.y * BN;
    const int tid = threadIdx.x;
    const int ttm = tid & 15, ttn = tid >> 4;

    float acc[8][4];
    #pragma unroll
    for (int i = 0; i < 8; ++i)
        #pragma unroll
        for (int j = 0; j < 4; ++j) acc[i][j] = 0.f;

    for (int k0 = 0; k0 < K; k0 += BK) {
        for (int i = tid; i < BM * BK; i += 256) {
            int m = i >> 4, k = i & 15;
            int r = row0 + m, kk = k0 + k;
            float v = 0.f;
            if (r < M && kk < K)
                v = (kk < CIN) ? AL[(size_t)r * CIN + kk]
                               : AR[(size_t)r * CIN + (kk - CIN)];
            As[k][m] = v;
        }
        for (int i = tid; i < BN * BK; i += 256) {
            int n = i >> 4, k = i & 15;
            int c = col0 + n, kk = k0 + k;
            Bs[k][n] = (c < N && kk < K) ? W[(size_t)c * K + kk] : 0.f;
        }
        __syncthreads();
        #pragma unroll
        for (int k = 0; k < BK; ++k) {
            float4 a0 = *(const float4*)&As[k][ttm * 8];
            float4 a1 = *(const float4*)&As[k][ttm * 8 + 4];
            float4 b0 = *(const float4*)&Bs[k][ttn * 4];
            float av[8] = {a0.x, a0.y, a0.z, a0.w, a1.x, a1.y, a1.z, a1.w};
            float bv[4] = {b0.x, b0.y, b0.z, b0.w};
            #pragma unroll
            for (int i = 0; i < 8; ++i)
                #pragma unroll
                for (int j = 0; j < 4; ++j)
                    acc[i][j] += av[i] * bv[j];
        }
        __syncthreads();
    }

    float bv[4];
    #pragma unroll
    for (int j = 0; j < 4; ++j) bv[j] = bias[col0 + ttn * 4 + j];
    #pragma unroll
    for (int i = 0; i < 8; ++i) {
        int r = row0 + ttm * 8 + i;
        if (r < M) {
            float t0 = acc[i][0] + bv[0];
            float t1 = acc[i][1] + bv[1];
            float t2 = acc[i][2] + bv[2];
            float t3 = acc[i][3] + bv[3];
            if (RELU) {
                t0 = t0 > 0.f ? t0 : t0 * NEG_SLOPE;
                t1 = t1 > 0.f ? t1 : t1 * NEG_SLOPE;
                t2 = t2 > 0.f ? t2 : t2 * NEG_SLOPE;
                t3 = t3 > 0.f ? t3 : t3 * NEG_SLOPE;
            }
            float4 v; v.x = t0; v.y = t1; v.z = t2; v.w = t3;
            *(float4*)&C[(size_t)r * N + col0 + ttn * 4] = v;
        }
    }
}

// ---------- split-bf16 MFMA cat-GEMM, PRE-SPLIT A inputs (layer 2)
// A = cat((ALhi,ALlo),(ARhi,ARlo)); stage = pure copies; out = (Chi, Clo)
__global__ __launch_bounds__(256) void gemm_cat_mfma_ps_kernel(
        const unsigned short* __restrict__ ALhi, const unsigned short* __restrict__ ALlo,
        const unsigned short* __restrict__ ARhi, const unsigned short* __restrict__ ARlo,
        const short* __restrict__ Whi, const short* __restrict__ Wlo,
        const float* __restrict__ bias,
        unsigned short* __restrict__ Chi, unsigned short* __restrict__ Clo,
        int M, int N, int K, int CIN) {
    __shared__ short AsH[128][40], AsL[128][40];
    __shared__ short BsH[128][40], BsL[128][40];
    const int row0 = blockIdx.x * 128;
    const int n0 = blockIdx.y * 128;
    const int tid = threadIdx.x;
    const int w = tid >> 6;
    const int lane31 = tid & 31, lhalf = (tid & 63) >> 5;

    f32x16 acc[4];
    #pragma unroll
    for (int ci = 0; ci < 4; ++ci)
        #pragma unroll
        for (int r = 0; r < 16; ++r) acc[ci][r] = 0.f;

    for (int k0 = 0; k0 < K; k0 += 32) {
        const unsigned short* Ahi = (k0 < CIN) ? ALhi : ARhi;
        const unsigned short* Alo = (k0 < CIN) ? ALlo : ARlo;
        const int kb = (k0 < CIN) ? k0 : k0 - CIN;
        {   // stage A: pure copy of pre-split rows (16 elems/thread per buf)
            int row = tid >> 1, kq = (tid & 1) * 16;
            int r = row0 + row;
            uint4 h0 = {0,0,0,0}, h1v = {0,0,0,0}, l0 = {0,0,0,0}, l1 = {0,0,0,0};
            if (r < M) {
                const uint4* ph = (const uint4*)&Ahi[(size_t)r * CIN + kb + kq];
                const uint4* pl = (const uint4*)&Alo[(size_t)r * CIN + kb + kq];
                h0 = ph[0]; h1v = ph[1];
                l0 = pl[0]; l1 = pl[1];
            }
            *(uint4*)&AsH[row][kq] = h0;  *(uint4*)&AsH[row][kq + 8] = h1v;
            *(uint4*)&AsL[row][kq] = l0;  *(uint4*)&AsL[row][kq + 8] = l1;
        }
        {
            int n = tid & 127, half = tid >> 7;
            const short* src = half ? Wlo : Whi;
            const uint4* p = (const uint4*)&src[(size_t)(n0 + n) * K + k0];
            if (half) {
                #pragma unroll
                for (int q = 0; q < 4; ++q) *(uint4*)&BsL[n][q * 8] = p[q];
            } else {
                #pragma unroll
                for (int q = 0; q < 4; ++q) *(uint4*)&BsH[n][q * 8] = p[q];
            }
        }
        __syncthreads();
        #pragma unroll
        for (int ks = 0; ks < 2; ++ks) {
            int kofs = ks * 16 + lhalf * 8;
            bh8 aH = *(bh8*)&AsH[w * 32 + lane31][kofs];
            bh8 aL = *(bh8*)&AsL[w * 32 + lane31][kofs];
            #pragma unroll
            for (int ci = 0; ci < 4; ++ci) {
                bh8 bH = *(bh8*)&BsH[ci * 32 + lane31][kofs];
                bh8 bL = *(bh8*)&BsL[ci * 32 + lane31][kofs];
                acc[ci] = __builtin_amdgcn_mfma_f32_32x32x16_bf16(aH, bH, acc[ci], 0, 0, 0);
                acc[ci] = __builtin_amdgcn_mfma_f32_32x32x16_bf16(aH, bL, acc[ci], 0, 0, 0);
                acc[ci] = __builtin_amdgcn_mfma_f32_32x32x16_bf16(aL, bH, acc[ci], 0, 0, 0);
            }
        }
        __syncthreads();
    }

    #pragma unroll
    for (int ci = 0; ci < 4; ++ci) {
        int col = n0 + ci * 32 + lane31;
        float b = bias[col];
        #pragma unroll
        for (int r = 0; r < 16; ++r) {
            int row = row0 + w * 32 + (r & 3) + 8 * (r >> 2) + 4 * lhalf;
            if (row < M) {
                float v = acc[ci][r] + b;
                v = v > 0.f ? v : v * NEG_SLOPE;
                short h, l;
                splitf(v, h, l);
                Chi[(size_t)row * N + col] = (unsigned short)h;
                Clo[(size_t)row * N + col] = (unsigned short)l;
            }
        }
    }
}

// -------- split-bf16 MFMA cat-GEMM, f32 A (classifier; round-10 proven)
__global__ __launch_bounds__(256) void gemm_cat_mfma_kernel(
        const float* __restrict__ AL, const float* __restrict__ AR,
        const short* __restrict__ Whi, const short* __restrict__ Wlo,
        const float* __restrict__ bias, float* __restrict__ C,
        int M, int N, int K, int CIN) {
    __shared__ short AsH[128][40], AsL[128][40];
    __shared__ short BsH[128][40], BsL[128][40];
    const int row0 = blockIdx.x * 128;
    const int n0 = blockIdx.y * 128;
    const int tid = threadIdx.x;
    const int w = tid >> 6;
    const int lane31 = tid & 31, lhalf = (tid & 63) >> 5;

    f32x16 acc[4];
    #pragma unroll
    for (int ci = 0; ci < 4; ++ci)
        #pragma unroll
        for (int r = 0; r < 16; ++r) acc[ci][r] = 0.f;

    for (int k0 = 0; k0 < K; k0 += 32) {
        const float* Asrc = (k0 < CIN) ? AL : AR;
        const int kb = (k0 < CIN) ? k0 : k0 - CIN;
        {
            int row = tid >> 1, kq = (tid & 1) * 16;
            int r = row0 + row;
            float vv[16];
            #pragma unroll
            for (int i = 0; i < 16; ++i) vv[i] = 0.f;
            if (r < M) {
                const float* p = &Asrc[(size_t)r * CIN + kb + kq];
                #pragma unroll
                for (int q = 0; q < 4; ++q) {
                    float4 v = ((const float4*)p)[q];
                    vv[q * 4 + 0] = v.x; vv[q * 4 + 1] = v.y;
                    vv[q * 4 + 2] = v.z; vv[q * 4 + 3] = v.w;
                }
            }
            #pragma unroll
            for (int half = 0; half < 2; ++half) {
                bh8 h8, l8;
                #pragma unroll
                for (int i = 0; i < 8; ++i) {
                    short a, b;
                    splitf(vv[half * 8 + i], a, b);
                    h8[i] = a; l8[i] = b;
                }
                *(bh8*)&AsH[row][kq + half * 8] = h8;
                *(bh8*)&AsL[row][kq + half * 8] = l8;
            }
        }
        {
            int n = tid & 127, half = tid >> 7;
            const short* src = half ? Wlo : Whi;
            const uint4* p = (const uint4*)&src[(size_t)(n0 + n) * K + k0];
            if (half) {
                #pragma unroll
                for (int q = 0; q < 4; ++q) *(uint4*)&BsL[n][q * 8] = p[q];
            } else {
                #pragma unroll
                for (int q = 0; q < 4; ++q) *(uint4*)&BsH[n][q * 8] = p[q];
            }
        }
        __syncthreads();
        #pragma unroll
        for (int ks = 0; ks < 2; ++ks) {
            int kofs = ks * 16 + lhalf * 8;
            bh8 aH = *(bh8*)&AsH[w * 32 + lane31][kofs];
            bh8 aL = *(bh8*)&AsL[w * 32 + lane31][kofs];
            #pragma unroll
            for (int ci = 0; ci < 4; ++ci) {
                bh8 bH = *(bh8*)&BsH[ci * 32 + lane31][kofs];
                bh8 bL = *(bh8*)&BsL[ci * 32 + lane31][kofs];
                acc[ci] = __builtin_amdgcn_mfma_f32_32x32x16_bf16(aH, bH, acc[ci], 0, 0, 0);
                acc[ci] = __builtin_amdgcn_mfma_f32_32x32x16_bf16(aH, bL, acc[ci], 0, 0, 0);
                acc[ci] = __builtin_amdgcn_mfma_f32_32x32x16_bf16(aL, bH, acc[ci], 0, 0, 0);
            }
        }
        __syncthreads();
    }

    #pragma unroll
    for (int ci = 0; ci < 4; ++ci) {
        int col = n0 + ci * 32 + lane31;
        float b = bias[col];
        #pragma unroll
        for (int r = 0; r < 16; ++r) {
            int row = row0 + w * 32 + (r & 3) + 8 * (r >> 2) + 4 * lhalf;
            if (row < M) {
                float v = acc[ci][r] + b;
                v = v > 0.f ? v : v * NEG_SLOPE;
                C[(size_t)row * N + col] = v;
            }
        }
    }
}

// ---- layer-3 GEMM + pool v3: pre-split A, K-tile 16, ~37KB LDS (3 blocks/CU),
//      named-register prefetch, red arrays union'd onto A staging LDS
template<int CIN>
__global__ __launch_bounds__(512) void gemm_pool_mfma3_kernel(
        const unsigned short* __restrict__ ALhi, const unsigned short* __restrict__ ALlo,
        const unsigned short* __restrict__ ARhi, const unsigned short* __restrict__ ARlo,
        const short* __restrict__ Whi, const short* __restrict__ Wlo,
        const float* __restrict__ bias, float* __restrict__ gout,
        int npg, int NCH) {
    __shared__ short AsH[128][24], AsL[128][24];   // 48B rows (16B-aligned)
    __shared__ short BsH[256][24], BsL[256][24];
    const int g2 = blockIdx.x * 2;
    constexpr int K = 2 * CIN;
    constexpr int NT = K / 16;
    const int tid = threadIdx.x;
    const int w = tid >> 6;
    const int lane31 = tid & 31, lhalf = (tid & 63) >> 5;
    const int rt = w & 3, cb = (w >> 2) * 4;
    const int arow = tid >> 2, akq = (tid & 3) * 4;     // 4 bf16 (8B) per buf
    const int agrow = arow >> 6, ar = arow & 63;
    const int bn = tid & 255, bhalf = tid >> 8;         // 16 bf16 (32B) per row

    f32x16 acc[4];
    #pragma unroll
    for (int ci = 0; ci < 4; ++ci)
        #pragma unroll
        for (int r = 0; r < 16; ++r) acc[ci][r] = 0.f;

    const size_t abase = ((size_t)(g2 + agrow) * npg + ar) * CIN + akq;
    const short* srcw = bhalf ? Wlo : Whi;

    uint2 cAh = {0,0}, cAl = {0,0};
    uint4 cB0, cB1;
    {   // tile 0 (k0 = 0 < CIN)
        if (ar < npg) {
            cAh = *(const uint2*)&ALhi[abase];
            cAl = *(const uint2*)&ALlo[abase];
        }
        const uint4* pb = (const uint4*)&srcw[(size_t)bn * K];
        cB0 = pb[0]; cB1 = pb[1];
    }

    #pragma unroll
    for (int t = 0; t < NT; ++t) {
        // write phase: pure copies (inputs pre-split)
        *(uint2*)&AsH[arow][akq] = cAh;
        *(uint2*)&AsL[arow][akq] = cAl;
        if (bhalf) {
            *(uint4*)&BsL[bn][0] = cB0; *(uint4*)&BsL[bn][8] = cB1;
        } else {
            *(uint4*)&BsH[bn][0] = cB0; *(uint4*)&BsH[bn][8] = cB1;
        }
        __syncthreads();
        // prefetch tile t+1 (named regs); latency hides under MFMA
        uint2 nAh = {0,0}, nAl = {0,0};
        uint4 nB0 = {0,0,0,0}, nB1 = {0,0,0,0};
        if (t + 1 < NT) {
            const int k0 = (t + 1) * 16;
            const unsigned short* Ahi = (k0 < CIN) ? ALhi : ARhi;
            const unsigned short* Alo = (k0 < CIN) ? ALlo : ARlo;
            const int kb = (k0 < CIN) ? k0 : k0 - CIN;
            if (ar < npg) {
                nAh = *(const uint2*)&Ahi[abase + kb];
                nAl = *(const uint2*)&Alo[abase + kb];
            }
            const uint4* pb = (const uint4*)&srcw[(size_t)bn * K + k0];
            nB0 = pb[0]; nB1 = pb[1];
        }
        {   // MFMA: one K=16 step
            int kofs = lhalf * 8;
            bh8 aH = *(bh8*)&AsH[rt * 32 + lane31][kofs];
            bh8 aL = *(bh8*)&AsL[rt * 32 + lane31][kofs];
            #pragma unroll
            for (int ci = 0; ci < 4; ++ci) {
                bh8 bH = *(bh8*)&BsH[(cb + ci) * 32 + lane31][kofs];
                bh8 bL = *(bh8*)&BsL[(cb + ci) * 32 + lane31][kofs];
                acc[ci] = __builtin_amdgcn_mfma_f32_32x32x16_bf16(aH, bH, acc[ci], 0, 0, 0);
                acc[ci] = __builtin_amdgcn_mfma_f32_32x32x16_bf16(aH, bL, acc[ci], 0, 0, 0);
                acc[ci] = __builtin_amdgcn_mfma_f32_32x32x16_bf16(aL, bH, acc[ci], 0, 0, 0);
            }
        }
        __syncthreads();
        if (t + 1 < NT) { cAh = nAh; cAl = nAl; cB0 = nB0; cB1 = nB1; }
    }

    // red arrays union'd onto A-staging LDS (dead after last barrier)
    float (*redS)[258] = (float(*)[258])&AsH[0][0];   // 4*258*4 = 4128 <= 6144
    float (*redM)[258] = (float(*)[258])&AsL[0][0];

    #pragma unroll
    for (int ci = 0; ci < 4; ++ci) {
        int col = (cb + ci) * 32 + lane31;
        float b = bias[col];
        float ls = 0.f, lm = -__builtin_huge_valf();
        #pragma unroll
        for (int r = 0; r < 16; ++r) {
            int crow = (r & 3) + 8 * (r >> 2) + 4 * lhalf;
            int grow = (rt & 1) * 32 + crow;
            if (grow < npg) {
                float v = acc[ci][r] + b;
                v = v > 0.f ? v : v * NEG_SLOPE;
                ls += v;
                lm = fmaxf(lm, v);
            }
        }
        ls += __shfl_xor(ls, 32);
        lm = fmaxf(lm, __shfl_xor(lm, 32));
        if (lhalf == 0) { redS[rt][col] = ls; redM[rt][col] = lm; }
    }
    __syncthreads();
    {
        int c = tid & 255, gi = tid >> 8;
        float s = redS[gi * 2][c] + redS[gi * 2 + 1][c];
        float m = fmaxf(redM[gi * 2][c], redM[gi * 2 + 1][c]);
        gout[(size_t)(g2 + gi) * (2 * NCH) + c] = s / (float)npg;
        gout[(size_t)(g2 + gi) * (2 * NCH) + NCH + c] = m;
    }
}

// ------------------------------------------------------- final 64->1 layer
__global__ void final_kernel(const float* __restrict__ c2, const float* __restrict__ Wc3,
                             const float* __restrict__ bc3, float* __restrict__ out, int G) {
    int g = blockIdx.x * (blockDim.x >> 6) + (threadIdx.x >> 6);
    int lane = threadIdx.x & 63;
    if (g >= G) return;
    float v = c2[(size_t)g * 64 + lane] * Wc3[lane];
    #pragma unroll
    for (int o = 32; o > 0; o >>= 1) v += __shfl_down(v, o);
    if (lane == 0) out[g] = v + bc3[0];
}

// ---------------------------------------------------------------- launcher
extern "C" void kernel_launch(void* const* d_in, const int* in_sizes, int n_in,
                              void* d_out, int out_size, void* d_ws, size_t ws_size,
                              hipStream_t stream) {
    const float* x   = (const float*)d_in[0];
    const int* ei    = (const int*)d_in[1];
    const float* W1l = (const float*)d_in[4];
    const float* b1  = (const float*)d_in[5];
    const float* W1r = (const float*)d_in[6];
    const float* W2l = (const float*)d_in[7];
    const float* b2  = (const float*)d_in[8];
    const float* W2r = (const float*)d_in[9];
    const float* W3l = (const float*)d_in[10];
    const float* b3  = (const float*)d_in[11];
    const float* W3r = (const float*)d_in[12];
    const float* Wc1 = (const float*)d_in[13];
    const float* bc1 = (const float*)d_in[14];
    const float* Wc2 = (const float*)d_in[15];
    const float* bc2 = (const float*)d_in[16];
    const float* Wc3 = (const float*)d_in[17];
    const float* bc3 = (const float*)d_in[18];
    float* out = (float*)d_out;

    const int nodes = in_sizes[0] / 5;      // 100000  (< 2^17 for packed pairs)
    const int ne    = in_sizes[1] / 2;      // 1600000
    const int G     = out_size;             // 2000 (even)
    const int npg   = nodes / G;            // 50
    const int nb    = (nodes + 511) >> 9;   // 196 buckets (<=256)

    char* ws = (char*)d_ws;
    size_t pos = 0;
    auto take = [&](size_t bytes) -> char* {
        char* p = ws + pos;
        pos += (bytes + 255) & ~(size_t)255;
        return p;
    };
    int* off     = (int*)take((size_t)(nodes + 1) * 4);
    int* csr     = (int*)take((size_t)ne * 4);
    int* bcnt    = (int*)take(256 * 4);
    int* bcur    = (int*)take(256 * 4);
    int* boff    = (int*)take(257 * 4);
    short* Whi2  = (short*)take((size_t)128 * 128 * 2);
    short* Wlo2  = (short*)take((size_t)128 * 128 * 2);
    short* Whi3  = (short*)take((size_t)256 * 256 * 2);
    short* Wlo3  = (short*)take((size_t)256 * 256 * 2);
    short* WhiC  = (short*)take((size_t)128 * 512 * 2);
    short* WloC  = (short*)take((size_t)128 * 512 * 2);
    float* gbuf  = (float*)take((size_t)G * 512 * 4);
    float* c1    = (float*)take((size_t)G * 128 * 4);
    float* c2    = (float*)take((size_t)G * 64 * 4);
    // activation region (all bf16 hi/lo pairs), sized multiples of 256B:
    unsigned short* m1hi = (unsigned short*)take((size_t)nodes * 64 * 2);
    unsigned short* m1lo = (unsigned short*)take((size_t)nodes * 64 * 2);
    unsigned short* h1hi = (unsigned short*)take((size_t)nodes * 64 * 2);
    unsigned short* h1lo = (unsigned short*)take((size_t)nodes * 64 * 2);
    unsigned short* h2hi = (unsigned short*)take((size_t)nodes * 128 * 2);
    unsigned short* h2lo = (unsigned short*)take((size_t)nodes * 128 * 2);
    // m2 (25.6MB x2) aliases dead [m1hi|m1lo] and [h1hi|h1lo] after L2 GEMM
    unsigned short* m2hi = m1hi;
    unsigned short* m2lo = h1hi;
    unsigned* pairs = (unsigned*)m1hi;  // 6.4MB alias, dead before m1hi written

    if (pos > ws_size) {
        sentinel_kernel<<<(G + 255) / 256, 256, 0, stream>>>(out, G);
        return;
    }

    const int* src = ei;
    const int* dst = ei + ne;

    hipMemsetAsync(bcnt, 0, 512 * 4, stream);   // bcnt + bcur (adjacent)

    // ---- CSR build v3
    bucket_count_kernel<<<(ne + HIST_CH - 1) / HIST_CH, 256, 0, stream>>>(dst, bcnt, ne, nb);
    scan256_kernel<<<1, 256, 0, stream>>>(bcnt, boff, nb);
    bucket_scatter_kernel<<<(ne + SCAT_CH - 1) / SCAT_CH, 256, 0, stream>>>(
        src, dst, boff, bcur, pairs, ne, nb);
    bucket_sort_kernel<<<nb, 512, 0, stream>>>(pairs, boff, off, csr, nodes);

    pack_wsplit_kernel<<<(128 * 128 + 255) / 256, 256, 0, stream>>>(W2l, W2r, Whi2, Wlo2, 128, 128, 64);
    pack_wsplit_kernel<<<(256 * 256 + 255) / 256, 256, 0, stream>>>(W3l, W3r, Whi3, Wlo3, 256, 256, 128);
    pack_wsplit_kernel<<<(128 * 512 + 255) / 256, 256, 0, stream>>>(Wc1, Wc1, WhiC, WloC, 128, 512, 512);

    // ---- layer 1 fused: h1 = lrelu(W1l·mean(x) + W1r·x + b1)  -> (h1hi, h1lo)
    sage1_kernel<<<(nodes + 3) / 4, 256, 0, stream>>>(x, off, csr, W1l, W1r, b1,
                                                      h1hi, h1lo, nodes);

    // ---- layer 2: [mean(h1)|h1] (K=128) -> 128  -> (h2hi, h2lo)
    agg_bf16_kernel<64><<<(nodes + 3) / 4, 256, 0, stream>>>(h1hi, off, csr, m1hi, m1lo, nodes);
    {
        dim3 g((nodes + 127) / 128, 1);
        gemm_cat_mfma_ps_kernel<<<g, 256, 0, stream>>>(m1hi, m1lo, h1hi, h1lo,
                                                       Whi2, Wlo2, b2, h2hi, h2lo,
                                                       nodes, 128, 128, 64);
    }
    // ---- layer 3: [mean(h2)|h2] (K=256) -> 256, fused pool (2 graphs/block)
    agg_bf16_kernel<128><<<(nodes + 3) / 4, 256, 0, stream>>>(h2hi, off, csr, m2hi, m2lo, nodes);
    gemm_pool_mfma3_kernel<128><<<G / 2, 512, 0, stream>>>(m2hi, m2lo, h2hi, h2lo,
                                                           Whi3, Wlo3, b3, gbuf, npg, 256);
    // ---- classifier: 512 -> 128 (MFMA) -> 64 (f32) -> 1
    {
        dim3 g((G + 127) / 128, 1);
        gemm_cat_mfma_kernel<<<g, 256, 0, stream>>>(gbuf, gbuf, WhiC, WloC, bc1, c1,
                                                    G, 128, 512, 512);
    }
    {
        dim3 g((G + BM - 1) / BM, 64 / BN);
        gemm_cat_kernel<true><<<g, 256, 0, stream>>>(c1, nullptr, Wc2, bc2, c2, G, 64, 128, 128);
    }
    final_kernel<<<(G + 3) / 4, 256, 0, stream>>>(c2, Wc3, bc3, out, G);
}